// Round 1
// baseline (1426.217 us; speedup 1.0000x reference)
//
#include <hip/hip_runtime.h>
#include <math.h>

#define Bn 16
#define Tn 2048
#define Cn 2048
#define HSn 256
#define SCALE 45.254833995939045f
#define NEG_BIG (-1e30f)
#define NT 16          // number of 128-tiles along T
#define NPAIR 136      // NT*(NT+1)/2
#define WN 524288      // Cn*HSn, elems per W matrix

typedef __attribute__((ext_vector_type(8))) short bf16x8;
typedef __attribute__((ext_vector_type(4))) float f32x4;
typedef unsigned short u16;
typedef unsigned int u32;

__device__ __forceinline__ u16 bf16_rn(float f) {
    u32 u = __float_as_uint(f);
    u += 0x7fffu + ((u >> 16) & 1u);
    return (u16)(u >> 16);
}
__device__ __forceinline__ float bf16_rn_f(float f) {
    return __uint_as_float((u32)bf16_rn(f) << 16);
}

// Barrier WITHOUT the vmcnt(0) drain __syncthreads() would emit.
// Own ds ops retired (lgkmcnt 0) -> cross-wave LDS ordering is safe; global
// reg-staged prefetch loads stay in flight across the barrier (the point).
__device__ __forceinline__ void bar_sync() {
    asm volatile("s_waitcnt lgkmcnt(0)" ::: "memory");
    __builtin_amdgcn_s_barrier();
    asm volatile("" ::: "memory");
}

// ---------------------------------------------------------------------------
// Kernel 0: split W matrices into transposed bf16 hi/lo: Wt[mat][n][k].
// ---------------------------------------------------------------------------
__global__ __launch_bounds__(256) void split_w_kernel(
    const float* __restrict__ Wk, const float* __restrict__ Wq,
    const float* __restrict__ Wv, u16* __restrict__ Wt)
{
    const int n = threadIdx.x, k = blockIdx.x, mat = blockIdx.y;
    const float* src = (mat == 0) ? Wk : (mat == 1) ? Wq : Wv;
    const float f = src[(long)k * HSn + n];
    const u32 u = __float_as_uint(f);
    const u16 hb = (u16)(u >> 16);                 // truncate -> hi
    const float fh = __uint_as_float(u & 0xffff0000u);
    const u16 lb = bf16_rn(f - fh);                // round residual -> lo
    u16* base = Wt + (long)mat * 2 * WN;
    base[(long)n * Cn + k] = hb;
    base[WN + (long)n * Cn + k] = lb;
}

// ---------------------------------------------------------------------------
// Kernel 1: QKV projections via split-bf16 MFMA — SOFTWARE-PIPELINED.
// Reg-staged prefetch of next 128x32 half-tile (X fp32 + Wt bf16) issued
// before the current half-tile's convert/LDS/MFMA phase; raw s_barrier (no
// vmcnt drain) keeps those loads in flight across barriers. Unroll x2 with
// A/B register sets so all indexing is compile-time.
// ---------------------------------------------------------------------------
__global__ __launch_bounds__(256) void projm_kernel(
    const float* __restrict__ X, const u16* __restrict__ Wt,
    u16* __restrict__ Khi, u16* __restrict__ Klo,
    u16* __restrict__ Qhi, u16* __restrict__ Qlo, u16* __restrict__ Vbf)
{
    __shared__ u16 Ahi[4096], Alo[4096], Bhi[4096], Blo[4096];  // 32 KB

    const int tid = threadIdx.x, l = tid & 63, w = tid >> 6;
    const int wm = w & 1, wn = w >> 1;
    const int z = blockIdx.z;
    const int m0 = blockIdx.x * 128, n0 = blockIdx.y * 128;
    const u16* Wthi = Wt + (long)z * 2 * WN;

    // Per-thread element offsets (fit in int: X <= 6.7e7 elems, Wt <= 2^21).
    int xoff[4], aoff[4], woff[4], boff[4];
    #pragma unroll
    for (int p = 0; p < 4; ++p) {
        const int idx4 = p * 256 + tid;     // 0..1023
        const int row  = idx4 >> 3;         // 0..127
        const int kk4  = (idx4 & 7) * 4;    // 0,4,...,28
        xoff[p] = (m0 + row) * Cn + kk4;
        aoff[p] = (row >> 4) * 512 + (((row & 15) | ((kk4 >> 3) << 4)) * 8) + (kk4 & 7);
        // W chunk: c = p*4 + w in [4p, 4p+3] -> half = p>>1 (compile-time!)
        const int cc = (p & 1) * 4 + w;     // 0..7
        woff[p] = (p >> 1) * WN + (n0 + cc * 16 + (l & 15)) * Cn + ((l >> 4) << 3);
        boff[p] = cc * 512 + l * 8;
    }

    f32x4 acc[4][4];
    #pragma unroll
    for (int a = 0; a < 4; ++a)
        #pragma unroll
        for (int bb = 0; bb < 4; ++bb)
            #pragma unroll
            for (int r = 0; r < 4; ++r) acc[a][bb][r] = 0.f;

    float4 xA[4], xB[4];
    uint4  wA[4], wB[4];

    auto load_tile = [&](float4 (&xr)[4], uint4 (&wr)[4], int k0) {
        #pragma unroll
        for (int p = 0; p < 4; ++p)
            xr[p] = *(const float4*)(X + xoff[p] + k0);
        #pragma unroll
        for (int p = 0; p < 4; ++p)
            if (p < 2 || z != 2)            // lo-half W unused for V
                wr[p] = *(const uint4*)(Wthi + woff[p] + k0);
    };

    auto compute_tile = [&](const float4 (&xr)[4], const uint4 (&wr)[4]) {
        bar_sync();                          // prev tile's LDS reads retired
        // --- convert X regs -> bf16 hi/lo, write frag-native LDS ---
        #pragma unroll
        for (int p = 0; p < 4; ++p) {
            const float xf[4] = {xr[p].x, xr[p].y, xr[p].z, xr[p].w};
            ushort4 h4, l4;
            #pragma unroll
            for (int c = 0; c < 4; ++c) {
                const u32 u = __float_as_uint(xf[c]);
                ((u16*)&h4)[c] = (u16)(u >> 16);
                const float fh = __uint_as_float(u & 0xffff0000u);
                ((u16*)&l4)[c] = bf16_rn(xf[c] - fh);
            }
            *(ushort4*)(Ahi + aoff[p]) = h4;
            if (z != 2) *(ushort4*)(Alo + aoff[p]) = l4;
        }
        #pragma unroll
        for (int p = 0; p < 4; ++p)
            if (p < 2 || z != 2)
                *(uint4*)(((p >> 1) ? Blo : Bhi) + boff[p]) = wr[p];
        bar_sync();                          // writes visible to all waves
        // --- frag reads + MFMA (identical to validated version) ---
        bf16x8 bh[4], bl[4];
        #pragma unroll
        for (int nt = 0; nt < 4; ++nt) {
            bh[nt] = *(const bf16x8*)(Bhi + (wn * 4 + nt) * 512 + l * 8);
            if (z != 2) bl[nt] = *(const bf16x8*)(Blo + (wn * 4 + nt) * 512 + l * 8);
        }
        #pragma unroll
        for (int mt = 0; mt < 4; ++mt) {
            const bf16x8 ah = *(const bf16x8*)(Ahi + (wm * 4 + mt) * 512 + l * 8);
            if (z != 2) {
                const bf16x8 al = *(const bf16x8*)(Alo + (wm * 4 + mt) * 512 + l * 8);
                #pragma unroll
                for (int nt = 0; nt < 4; ++nt) {
                    acc[mt][nt] = __builtin_amdgcn_mfma_f32_16x16x32_bf16(ah, bh[nt], acc[mt][nt], 0, 0, 0);
                    acc[mt][nt] = __builtin_amdgcn_mfma_f32_16x16x32_bf16(ah, bl[nt], acc[mt][nt], 0, 0, 0);
                    acc[mt][nt] = __builtin_amdgcn_mfma_f32_16x16x32_bf16(al, bh[nt], acc[mt][nt], 0, 0, 0);
                }
            } else {
                #pragma unroll
                for (int nt = 0; nt < 4; ++nt)
                    acc[mt][nt] = __builtin_amdgcn_mfma_f32_16x16x32_bf16(ah, bh[nt], acc[mt][nt], 0, 0, 0);
            }
        }
    };

    // prologue: tile 0 in flight
    load_tile(xA, wA, 0);

    #pragma unroll 1
    for (int k0 = 0; k0 < Cn; k0 += 64) {
        load_tile(xB, wB, k0 + 32);          // prefetch half-tile k0+32
        compute_tile(xA, wA);                // consume half-tile k0
        if (k0 + 64 < Cn)
            load_tile(xA, wA, k0 + 64);      // prefetch half-tile k0+64
        compute_tile(xB, wB);                // consume half-tile k0+32
    }

    // --- epilogue: C/D layout col=l&15, row=(l>>4)*4+r ---
    const int quad = (l >> 4) * 4, col = l & 15;
    if (z == 2) {
        #pragma unroll
        for (int mt = 0; mt < 4; ++mt)
            #pragma unroll
            for (int nt = 0; nt < 4; ++nt)
                #pragma unroll
                for (int r = 0; r < 4; ++r) {
                    const long i = m0 + wm * 64 + mt * 16 + quad + r;
                    const int  j = n0 + wn * 64 + nt * 16 + col;
                    Vbf[i * HSn + j] = bf16_rn(acc[mt][nt][r]);
                }
    } else {
        u16* Ohi = z ? Qhi : Khi;
        u16* Olo = z ? Qlo : Klo;
        #pragma unroll
        for (int mt = 0; mt < 4; ++mt)
            #pragma unroll
            for (int nt = 0; nt < 4; ++nt)
                #pragma unroll
                for (int r = 0; r < 4; ++r) {
                    const float f = acc[mt][nt][r];
                    const u32 u = __float_as_uint(f);
                    const u16 hb = (u16)(u >> 16);
                    const float fh = __uint_as_float(u & 0xffff0000u);
                    const u16 lb = bf16_rn(f - fh);
                    const long i = m0 + wm * 64 + mt * 16 + quad + r;
                    const int  j = n0 + wn * 64 + nt * 16 + col;
                    Ohi[i * HSn + j] = hb;
                    Olo[i * HSn + j] = lb;
                }
    }
}

// ---------------------------------------------------------------------------
// Shared: 128x128 score tile via split-bf16 MFMA (validated R3).
// ---------------------------------------------------------------------------
__device__ __forceinline__ void score_tile_mfma(
    const u16* __restrict__ Khi, const u16* __restrict__ Klo,
    const u16* __restrict__ Qhi, const u16* __restrict__ Qlo,
    long base, int i0, int j0,
    u16* Abuf, u16* Bbuf, f32x4 (&acc)[4][4], int tid)
{
    const int l = tid & 63, w = tid >> 6;
    const int wm = w & 1, wn = w >> 1;
    const int lrow = l & 15, lk8 = (l >> 4) << 3;

    #pragma unroll
    for (int a = 0; a < 4; ++a)
        #pragma unroll
        for (int bb = 0; bb < 4; ++bb)
            #pragma unroll
            for (int r = 0; r < 4; ++r) acc[a][bb][r] = 0.f;

    for (int ks = 0; ks < 8; ++ks) {
        const int h0 = ks * 32;
        #pragma unroll
        for (int q = 0; q < 8; ++q) {
            const int c    = (w << 3) | q;
            const int side = c >> 4;          // 0:K(A) 1:Q(B)
            const int cc   = c & 15;
            const int half = cc & 1;          // 0:hi 1:lo
            const int mt   = cc >> 1;         // 0..7 -> 16-row group
            const u16* src = side ? (half ? Qlo : Qhi) : (half ? Klo : Khi);
            const int row  = (side ? j0 : i0) + mt * 16 + lrow;
            const uint4 v  = *(const uint4*)(src + base + (long)row * HSn + h0 + lk8);
            u16* dst = (side ? Bbuf : Abuf) + cc * 512 + l * 8;
            *(uint4*)dst = v;
        }
        __syncthreads();
        bf16x8 bh[4], bl[4];
        #pragma unroll
        for (int nt = 0; nt < 4; ++nt) {
            const int c2 = (wn * 4 + nt) * 2;
            bh[nt] = *(const bf16x8*)(Bbuf + (c2    ) * 512 + l * 8);
            bl[nt] = *(const bf16x8*)(Bbuf + (c2 + 1) * 512 + l * 8);
        }
        #pragma unroll
        for (int mt = 0; mt < 4; ++mt) {
            const int c2 = (wm * 4 + mt) * 2;
            const bf16x8 ah = *(const bf16x8*)(Abuf + (c2    ) * 512 + l * 8);
            const bf16x8 al = *(const bf16x8*)(Abuf + (c2 + 1) * 512 + l * 8);
            #pragma unroll
            for (int nt = 0; nt < 4; ++nt) {
                acc[mt][nt] = __builtin_amdgcn_mfma_f32_16x16x32_bf16(ah, bh[nt], acc[mt][nt], 0, 0, 0);
                acc[mt][nt] = __builtin_amdgcn_mfma_f32_16x16x32_bf16(ah, bl[nt], acc[mt][nt], 0, 0, 0);
                acc[mt][nt] = __builtin_amdgcn_mfma_f32_16x16x32_bf16(al, bh[nt], acc[mt][nt], 0, 0, 0);
            }
        }
        __syncthreads();
    }
}

__device__ __forceinline__ void pair_from_p(int p, int& it, int& jt) {
    it = (int)((sqrtf(8.f * (float)p + 1.f) - 1.f) * 0.5f);
    while ((it + 1) * (it + 2) / 2 <= p) ++it;
    while (it * (it + 1) / 2 > p) --it;
    jt = p - it * (it + 1) / 2;
}

// ---------------------------------------------------------------------------
// Kernel 2a: per-(pair, column) partial softmax stats (m, d), bf16.
// ---------------------------------------------------------------------------
__global__ __launch_bounds__(256) void stats1_kernel(
    const u16* __restrict__ Khi, const u16* __restrict__ Klo,
    const u16* __restrict__ Qhi, const u16* __restrict__ Qlo,
    u16* __restrict__ Pm, u16* __restrict__ Pd)
{
    __shared__ u16 Abuf[8192], Bbuf[8192];
    __shared__ float redm[2][128], redd[2][128];

    const int tid = threadIdx.x, l = tid & 63, w = tid >> 6;
    const int wm = w & 1, wn = w >> 1;
    const int b = blockIdx.y;
    int it, jt; pair_from_p(blockIdx.x, it, jt);
    const long base = (long)b * Tn * HSn;

    f32x4 acc[4][4];
    score_tile_mfma(Khi, Klo, Qhi, Qlo, base, it * 128, jt * 128, Abuf, Bbuf, acc, tid);

    const int rquad = (l >> 4) * 4, col = l & 15;
    #pragma unroll
    for (int nt = 0; nt < 4; ++nt) {
        const int j = jt * 128 + wn * 64 + nt * 16 + col;
        float m = NEG_BIG;
        #pragma unroll
        for (int mt = 0; mt < 4; ++mt)
            #pragma unroll
            for (int r = 0; r < 4; ++r) {
                const int i = it * 128 + wm * 64 + mt * 16 + rquad + r;
                const float sv = (i >= j) ? acc[mt][nt][r] * SCALE : NEG_BIG;
                acc[mt][nt][r] = sv;
                m = fmaxf(m, sv);
            }
        m = fmaxf(m, __shfl_xor(m, 16));
        m = fmaxf(m, __shfl_xor(m, 32));
        float d = 0.f;
        #pragma unroll
        for (int mt = 0; mt < 4; ++mt)
            #pragma unroll
            for (int r = 0; r < 4; ++r)
                d += __expf(acc[mt][nt][r] - m);
        d += __shfl_xor(d, 16);
        d += __shfl_xor(d, 32);
        if (l < 16) {
            redm[wm][wn * 64 + nt * 16 + l] = m;
            redd[wm][wn * 64 + nt * 16 + l] = d;
        }
    }
    __syncthreads();
    if (tid < 128) {
        const float m0 = redm[0][tid], m1 = redm[1][tid];
        const float d0 = redd[0][tid], d1 = redd[1][tid];
        const float M = fmaxf(m0, m1);
        float D = d0 * __expf(m0 - M) + d1 * __expf(m1 - M);
        const float Mb = bf16_rn_f(M);
        D *= __expf(M - Mb);      // rebase to the rounded max we will store
        const long idx = ((long)b * NPAIR + blockIdx.x) * 128 + tid;
        Pm[idx] = (u16)(__float_as_uint(Mb) >> 16);
        Pd[idx] = bf16_rn(D);
    }
}

// ---------------------------------------------------------------------------
// Kernel 2b: merge partials over i-tiles -> Ms, Rd.
// ---------------------------------------------------------------------------
__global__ __launch_bounds__(128) void stats2_kernel(
    const u16* __restrict__ Pm, const u16* __restrict__ Pd,
    float* __restrict__ Ms, float* __restrict__ Rd)
{
    const int b = blockIdx.y, jt = blockIdx.x, jl = threadIdx.x;  // 128 threads
    float M = NEG_BIG, D = 0.f;
    for (int it = jt; it < NT; ++it) {
        const int p = it * (it + 1) / 2 + jt;
        const long idx = ((long)b * NPAIR + p) * 128 + jl;
        const float m = __uint_as_float((u32)Pm[idx] << 16);
        const float d = __uint_as_float((u32)Pd[idx] << 16);
        const float Mn = fmaxf(M, m);
        D = D * __expf(M - Mn) + d * __expf(m - Mn);
        M = Mn;
    }
    Ms[(long)b * Tn + jt * 128 + jl] = M;
    Rd[(long)b * Tn + jt * 128 + jl] = 1.f / D;
}

// ---------------------------------------------------------------------------
// Kernel 3: per-pair output partials (validated R3).
// ---------------------------------------------------------------------------
__global__ __launch_bounds__(256) void out_kernel(
    const u16* __restrict__ Khi, const u16* __restrict__ Klo,
    const u16* __restrict__ Qhi, const u16* __restrict__ Qlo,
    const u16* __restrict__ Vbf, const float* __restrict__ Ms,
    const float* __restrict__ Rd, float* __restrict__ Out)
{
    __shared__ u16 u_lds[34816];
    u16* Abuf = u_lds;
    u16* Bbuf = u_lds + 8192;
    u16* Pf   = u_lds;           // [128][136] bf16
    u16* Vt   = u_lds + 17408;   // [128][136] bf16 (h-major)

    const int tid = threadIdx.x, l = tid & 63, w = tid >> 6;
    const int wm = w & 1, wn = w >> 1;
    const int b = blockIdx.y;
    int it, jt; pair_from_p(blockIdx.x, it, jt);
    const long base = (long)b * Tn * HSn;

    f32x4 acc[4][4];
    score_tile_mfma(Khi, Klo, Qhi, Qlo, base, it * 128, jt * 128, Abuf, Bbuf, acc, tid);

    const int rquad = (l >> 4) * 4, col = l & 15;
    float mj[4], rj[4];
    #pragma unroll
    for (int nt = 0; nt < 4; ++nt) {
        const int j = jt * 128 + wn * 64 + nt * 16 + col;
        mj[nt] = Ms[(long)b * Tn + j];
        rj[nt] = Rd[(long)b * Tn + j];
    }
    #pragma unroll
    for (int nt = 0; nt < 4; ++nt) {
        const int j = jt * 128 + wn * 64 + nt * 16 + col;
        #pragma unroll
        for (int mt = 0; mt < 4; ++mt)
            #pragma unroll
            for (int r = 0; r < 4; ++r) {
                const int i = it * 128 + wm * 64 + mt * 16 + rquad + r;
                const float pv = (i >= j)
                    ? __expf(acc[mt][nt][r] * SCALE - mj[nt]) * rj[nt] : 0.f;
                Pf[(wm * 64 + mt * 16 + rquad + r) * 136 + wn * 64 + nt * 16 + col]
                    = bf16_rn(pv);
            }
    }

    const int lrow = l & 15, lk8 = (l >> 4) << 3;
    for (int ph = 0; ph < 2; ++ph) {
        __syncthreads();
        {
            const int jj = tid & 127, hs = (tid >> 7) * 64;
            const long vbase = ((long)b * Tn + jt * 128 + jj) * HSn + ph * 128 + hs;
            #pragma unroll
            for (int qq = 0; qq < 8; ++qq) {
                union { uint4 v; u16 s[8]; } uu;
                uu.v = *(const uint4*)(Vbf + vbase + qq * 8);
                #pragma unroll
                for (int e = 0; e < 8; ++e)
                    Vt[(hs + qq * 8 + e) * 136 + jj] = uu.s[e];
            }
        }
        __syncthreads();

        f32x4 o[4][4];
        #pragma unroll
        for (int a = 0; a < 4; ++a)
            #pragma unroll
            for (int bb = 0; bb < 4; ++bb)
                #pragma unroll
                for (int r = 0; r < 4; ++r) o[a][bb][r] = 0.f;

        #pragma unroll
        for (int kj = 0; kj < 4; ++kj) {
            bf16x8 aP[4];
            #pragma unroll
            for (int mt = 0; mt < 4; ++mt)
                aP[mt] = *(const bf16x8*)(Pf + (wm * 64 + mt * 16 + lrow) * 136 + kj * 32 + lk8);
            #pragma unroll
            for (int nt = 0; nt < 4; ++nt) {
                const bf16x8 bV = *(const bf16x8*)(Vt + (wn * 64 + nt * 16 + lrow) * 136 + kj * 32 + lk8);
                #pragma unroll
                for (int mt = 0; mt < 4; ++mt)
                    o[mt][nt] = __builtin_amdgcn_mfma_f32_16x16x32_bf16(aP[mt], bV, o[mt][nt], 0, 0, 0);
            }
        }
        #pragma unroll
        for (int mt = 0; mt < 4; ++mt)
            #pragma unroll
            for (int nt = 0; nt < 4; ++nt)
                #pragma unroll
                for (int r = 0; r < 4; ++r) {
                    const int i = it * 128 + wm * 64 + mt * 16 + rquad + r;
                    const int h = ph * 128 + wn * 64 + nt * 16 + col;
                    atomicAdd(&Out[((long)b * Tn + i) * HSn + h], o[mt][nt][r]);
                }
    }
}

extern "C" void kernel_launch(void* const* d_in, const int* in_sizes, int n_in,
                              void* d_out, int out_size, void* d_ws, size_t ws_size,
                              hipStream_t stream) {
    const float* X  = (const float*)d_in[0];
    const float* Wk = (const float*)d_in[1];
    const float* Wq = (const float*)d_in[2];
    const float* Wv = (const float*)d_in[3];

    const long nE = (long)Bn * Tn * HSn;          // 8,388,608 elements
    u16* Khi = (u16*)d_ws;
    u16* Klo = Khi + nE;
    u16* Qhi = Khi + 2 * nE;
    u16* Qlo = Khi + 3 * nE;
    u16* Vbf = Khi + 4 * nE;
    u16* Wt  = Khi + 5 * nE;                      // 6 arrays of WN (hi/lo x K,Q,V)
    u16* Pm  = Wt + 6L * WN;                      // [B][NPAIR][128] bf16
    u16* Pd  = Pm + (long)Bn * NPAIR * 128;
    float* Ms = (float*)(Pd + (long)Bn * NPAIR * 128);
    float* Rd = Ms + (long)Bn * Tn;
    // total ws ~= 91.5 MiB (< 96.6 MiB proven in R2)

    split_w_kernel<<<dim3(Cn, 3), 256, 0, stream>>>(Wk, Wq, Wv, Wt);
    projm_kernel<<<dim3((Bn * Tn) / 128, HSn / 128, 3), 256, 0, stream>>>(
        X, Wt, Khi, Klo, Qhi, Qlo, Vbf);
    stats1_kernel<<<dim3(NPAIR, Bn), 256, 0, stream>>>(Khi, Klo, Qhi, Qlo, Pm, Pd);
    stats2_kernel<<<dim3(NT, Bn), 128, 0, stream>>>(Pm, Pd, Ms, Rd);
    hipMemsetAsync(d_out, 0, (size_t)out_size * sizeof(float), stream);
    out_kernel<<<dim3(NPAIR, Bn), 256, 0, stream>>>(Khi, Klo, Qhi, Qlo, Vbf, Ms, Rd,
                                                    (float*)d_out);
}

// Round 2
// 1093.533 us; speedup vs baseline: 1.3042x; 1.3042x over previous
//
#include <hip/hip_runtime.h>
#include <math.h>

#define Bn 16
#define Tn 2048
#define Cn 2048
#define HSn 256
#define SCALE 45.254833995939045f
#define NEG_BIG (-1e30f)
#define NT 16          // number of 128-tiles along T
#define NPAIR 136      // NT*(NT+1)/2
#define WN 524288      // Cn*HSn, elems per W matrix

typedef __attribute__((ext_vector_type(8))) short bf16x8;
typedef __attribute__((ext_vector_type(4))) float f32x4;
typedef unsigned short u16;
typedef unsigned int u32;

__device__ __forceinline__ u16 bf16_rn(float f) {
    u32 u = __float_as_uint(f);
    u += 0x7fffu + ((u >> 16) & 1u);
    return (u16)(u >> 16);
}
__device__ __forceinline__ float bf16_rn_f(float f) {
    return __uint_as_float((u32)bf16_rn(f) << 16);
}

// async global->LDS, 16B per lane; LDS dst must be wave-uniform base (lane*16 implicit)
#define GLOAD_LDS16(gp, lp)                                                      \
    __builtin_amdgcn_global_load_lds(                                            \
        (const __attribute__((address_space(1))) unsigned int*)(gp),             \
        (__attribute__((address_space(3))) unsigned int*)(lp), 16, 0, 0)

// ---------------------------------------------------------------------------
// Kernel 0: split W matrices into transposed bf16 hi/lo: Wt[mat][n][k].
// Order: KH(0) KL(1) QH(2) QL(3) VH(4) VL(5), each WN elems.
// ---------------------------------------------------------------------------
__global__ __launch_bounds__(256) void split_w_kernel(
    const float* __restrict__ Wk, const float* __restrict__ Wq,
    const float* __restrict__ Wv, u16* __restrict__ Wt)
{
    const int n = threadIdx.x, k = blockIdx.x, mat = blockIdx.y;
    const float* src = (mat == 0) ? Wk : (mat == 1) ? Wq : Wv;
    const float f = src[(long)k * HSn + n];
    const u32 u = __float_as_uint(f);
    const u16 hb = (u16)(u >> 16);                 // truncate -> hi
    const float fh = __uint_as_float(u & 0xffff0000u);
    const u16 lb = bf16_rn(f - fh);                // round residual -> lo
    u16* base = Wt + (long)mat * 2 * WN;
    base[(long)n * Cn + k] = hb;
    base[WN + (long)n * Cn + k] = lb;
}

// ---------------------------------------------------------------------------
// Kernel 1: FUSED K/Q/V projection.
// Block = 64 m-rows x 128 n-cols, 4 waves (2x2), wave = 32m x 64n.
// Per k-step (BK=32): X tile converted to bf16 hi/lo ONCE (vs 6x before),
// all 5 W halves (KH,KL,QH,QL,VH) staged via global_load_lds width=16
// directly in frag-native order. acc: K,Q,V each 2x4 f32x4 = 96 VGPR.
// K,Q: 3-product split-bf16 (hi*hi + hi*lo + lo*hi); V: hi*hi.
// ---------------------------------------------------------------------------
__global__ __launch_bounds__(256, 2) void projm_fused_kernel(
    const float* __restrict__ X, const u16* __restrict__ Wt,
    u16* __restrict__ Khi, u16* __restrict__ Klo,
    u16* __restrict__ Qhi, u16* __restrict__ Qlo, u16* __restrict__ Vbf)
{
    __shared__ u16 Ahi[2048], Alo[2048];   // 64x32 bf16, frag-native, 4 KB each
    __shared__ u16 Bbuf[20480];            // 5 halves x 8 chunks x 512, 40 KB

    const int tid = threadIdx.x, l = tid & 63, w = tid >> 6;
    const int wm = w & 1, wn = w >> 1;
    const int m0 = blockIdx.x * 64, n0 = blockIdx.y * 128;

    // --- X staging offsets: 2 float4 per thread covering 64x32 ---
    int xoff[2], aoff[2];
    #pragma unroll
    for (int p = 0; p < 2; ++p) {
        const int idx4 = p * 256 + tid;     // 0..511
        const int row  = idx4 >> 3;         // 0..63
        const int kk4  = (idx4 & 7) * 4;    // 0,4,...,28
        xoff[p] = (m0 + row) * Cn + kk4;
        aoff[p] = (row >> 4) * 512 + (((row & 15) | ((kk4 >> 3) << 4)) * 8) + (kk4 & 7);
    }

    // --- W staging: 40 chunks (5 halves x 8 n-chunks); wave w owns g=w*10+j ---
    // per-lane global source addr; LDS dst = Bbuf + g*512 + lane*8 (implicit)
    int wgoff[10];
    const int lbase = w * 10 * 512;         // u16 offset of this wave's chunks
    #pragma unroll
    for (int j = 0; j < 10; ++j) {
        const int g    = w * 10 + j;        // 0..39
        const int half = g >> 3;            // 0:KH 1:KL 2:QH 3:QL 4:VH
        const int cc   = g & 7;             // n-chunk
        const int nrow = n0 + cc * 16 + (l & 15);
        wgoff[j] = half * WN + nrow * Cn + ((l >> 4) << 3);
    }

    f32x4 accK[2][4], accQ[2][4], accV[2][4];
    #pragma unroll
    for (int mt = 0; mt < 2; ++mt)
        #pragma unroll
        for (int nt = 0; nt < 4; ++nt)
            #pragma unroll
            for (int r = 0; r < 4; ++r) {
                accK[mt][nt][r] = 0.f; accQ[mt][nt][r] = 0.f; accV[mt][nt][r] = 0.f;
            }

    #pragma unroll 1
    for (int k0 = 0; k0 < Cn; k0 += 32) {
        // issue X loads first (deepest latency), then async W staging
        const float4 xv0 = *(const float4*)(X + xoff[0] + k0);
        const float4 xv1 = *(const float4*)(X + xoff[1] + k0);
        #pragma unroll
        for (int j = 0; j < 10; ++j)
            GLOAD_LDS16(Wt + wgoff[j] + k0, Bbuf + lbase + j * 512);

        // convert X -> bf16 hi/lo, write frag-native (waits only on xv loads)
        #pragma unroll
        for (int p = 0; p < 2; ++p) {
            const float4 xv = p ? xv1 : xv0;
            const float xf[4] = {xv.x, xv.y, xv.z, xv.w};
            ushort4 h4, l4;
            #pragma unroll
            for (int c = 0; c < 4; ++c) {
                const u32 u = __float_as_uint(xf[c]);
                ((u16*)&h4)[c] = (u16)(u >> 16);
                const float fh = __uint_as_float(u & 0xffff0000u);
                ((u16*)&l4)[c] = bf16_rn(xf[c] - fh);
            }
            *(ushort4*)(Ahi + aoff[p]) = h4;
            *(ushort4*)(Alo + aoff[p]) = l4;
        }
        __syncthreads();   // drains gload_lds (vmcnt) + A writes (lgkmcnt)

        // A fragments once, shared by K/Q/V
        bf16x8 ah[2], al[2];
        #pragma unroll
        for (int mt = 0; mt < 2; ++mt) {
            ah[mt] = *(const bf16x8*)(Ahi + (wm * 2 + mt) * 512 + l * 8);
            al[mt] = *(const bf16x8*)(Alo + (wm * 2 + mt) * 512 + l * 8);
        }
        // K: 3-product
        {
            bf16x8 bh[4], bl[4];
            #pragma unroll
            for (int nt = 0; nt < 4; ++nt) {
                bh[nt] = *(const bf16x8*)(Bbuf + (0 * 8 + wn * 4 + nt) * 512 + l * 8);
                bl[nt] = *(const bf16x8*)(Bbuf + (1 * 8 + wn * 4 + nt) * 512 + l * 8);
            }
            #pragma unroll
            for (int mt = 0; mt < 2; ++mt)
                #pragma unroll
                for (int nt = 0; nt < 4; ++nt) {
                    accK[mt][nt] = __builtin_amdgcn_mfma_f32_16x16x32_bf16(ah[mt], bh[nt], accK[mt][nt], 0, 0, 0);
                    accK[mt][nt] = __builtin_amdgcn_mfma_f32_16x16x32_bf16(ah[mt], bl[nt], accK[mt][nt], 0, 0, 0);
                    accK[mt][nt] = __builtin_amdgcn_mfma_f32_16x16x32_bf16(al[mt], bh[nt], accK[mt][nt], 0, 0, 0);
                }
        }
        // Q: 3-product
        {
            bf16x8 bh[4], bl[4];
            #pragma unroll
            for (int nt = 0; nt < 4; ++nt) {
                bh[nt] = *(const bf16x8*)(Bbuf + (2 * 8 + wn * 4 + nt) * 512 + l * 8);
                bl[nt] = *(const bf16x8*)(Bbuf + (3 * 8 + wn * 4 + nt) * 512 + l * 8);
            }
            #pragma unroll
            for (int mt = 0; mt < 2; ++mt)
                #pragma unroll
                for (int nt = 0; nt < 4; ++nt) {
                    accQ[mt][nt] = __builtin_amdgcn_mfma_f32_16x16x32_bf16(ah[mt], bh[nt], accQ[mt][nt], 0, 0, 0);
                    accQ[mt][nt] = __builtin_amdgcn_mfma_f32_16x16x32_bf16(ah[mt], bl[nt], accQ[mt][nt], 0, 0, 0);
                    accQ[mt][nt] = __builtin_amdgcn_mfma_f32_16x16x32_bf16(al[mt], bh[nt], accQ[mt][nt], 0, 0, 0);
                }
        }
        // V: hi only
        {
            bf16x8 bh[4];
            #pragma unroll
            for (int nt = 0; nt < 4; ++nt)
                bh[nt] = *(const bf16x8*)(Bbuf + (4 * 8 + wn * 4 + nt) * 512 + l * 8);
            #pragma unroll
            for (int mt = 0; mt < 2; ++mt)
                #pragma unroll
                for (int nt = 0; nt < 4; ++nt)
                    accV[mt][nt] = __builtin_amdgcn_mfma_f32_16x16x32_bf16(ah[mt], bh[nt], accV[mt][nt], 0, 0, 0);
        }
        __syncthreads();
    }

    // --- epilogue: C/D layout col=l&15, row=(l>>4)*4+r ---
    const int quad = (l >> 4) * 4, col = l & 15;
    #pragma unroll
    for (int mt = 0; mt < 2; ++mt)
        #pragma unroll
        for (int nt = 0; nt < 4; ++nt)
            #pragma unroll
            for (int r = 0; r < 4; ++r) {
                const long i = m0 + wm * 32 + mt * 16 + quad + r;
                const int  j = n0 + wn * 64 + nt * 16 + col;
                // K hi/lo
                {
                    const float f = accK[mt][nt][r];
                    const u32 u = __float_as_uint(f);
                    const u16 hb = (u16)(u >> 16);
                    const float fh = __uint_as_float(u & 0xffff0000u);
                    Khi[i * HSn + j] = hb;
                    Klo[i * HSn + j] = bf16_rn(f - fh);
                }
                // Q hi/lo
                {
                    const float f = accQ[mt][nt][r];
                    const u32 u = __float_as_uint(f);
                    const u16 hb = (u16)(u >> 16);
                    const float fh = __uint_as_float(u & 0xffff0000u);
                    Qhi[i * HSn + j] = hb;
                    Qlo[i * HSn + j] = bf16_rn(f - fh);
                }
                Vbf[i * HSn + j] = bf16_rn(accV[mt][nt][r]);
            }
}

// ---------------------------------------------------------------------------
// Shared: 128x128 score tile via split-bf16 MFMA (validated R3).
// ---------------------------------------------------------------------------
__device__ __forceinline__ void score_tile_mfma(
    const u16* __restrict__ Khi, const u16* __restrict__ Klo,
    const u16* __restrict__ Qhi, const u16* __restrict__ Qlo,
    long base, int i0, int j0,
    u16* Abuf, u16* Bbuf, f32x4 (&acc)[4][4], int tid)
{
    const int l = tid & 63, w = tid >> 6;
    const int wm = w & 1, wn = w >> 1;
    const int lrow = l & 15, lk8 = (l >> 4) << 3;

    #pragma unroll
    for (int a = 0; a < 4; ++a)
        #pragma unroll
        for (int bb = 0; bb < 4; ++bb)
            #pragma unroll
            for (int r = 0; r < 4; ++r) acc[a][bb][r] = 0.f;

    for (int ks = 0; ks < 8; ++ks) {
        const int h0 = ks * 32;
        #pragma unroll
        for (int q = 0; q < 8; ++q) {
            const int c    = (w << 3) | q;
            const int side = c >> 4;          // 0:K(A) 1:Q(B)
            const int cc   = c & 15;
            const int half = cc & 1;          // 0:hi 1:lo
            const int mt   = cc >> 1;         // 0..7 -> 16-row group
            const u16* src = side ? (half ? Qlo : Qhi) : (half ? Klo : Khi);
            const int row  = (side ? j0 : i0) + mt * 16 + lrow;
            const uint4 v  = *(const uint4*)(src + base + (long)row * HSn + h0 + lk8);
            u16* dst = (side ? Bbuf : Abuf) + cc * 512 + l * 8;
            *(uint4*)dst = v;
        }
        __syncthreads();
        bf16x8 bh[4], bl[4];
        #pragma unroll
        for (int nt = 0; nt < 4; ++nt) {
            const int c2 = (wn * 4 + nt) * 2;
            bh[nt] = *(const bf16x8*)(Bbuf + (c2    ) * 512 + l * 8);
            bl[nt] = *(const bf16x8*)(Bbuf + (c2 + 1) * 512 + l * 8);
        }
        #pragma unroll
        for (int mt = 0; mt < 4; ++mt) {
            const int c2 = (wm * 4 + mt) * 2;
            const bf16x8 ah = *(const bf16x8*)(Abuf + (c2    ) * 512 + l * 8);
            const bf16x8 al = *(const bf16x8*)(Abuf + (c2 + 1) * 512 + l * 8);
            #pragma unroll
            for (int nt = 0; nt < 4; ++nt) {
                acc[mt][nt] = __builtin_amdgcn_mfma_f32_16x16x32_bf16(ah, bh[nt], acc[mt][nt], 0, 0, 0);
                acc[mt][nt] = __builtin_amdgcn_mfma_f32_16x16x32_bf16(ah, bl[nt], acc[mt][nt], 0, 0, 0);
                acc[mt][nt] = __builtin_amdgcn_mfma_f32_16x16x32_bf16(al, bh[nt], acc[mt][nt], 0, 0, 0);
            }
        }
        __syncthreads();
    }
}

__device__ __forceinline__ void pair_from_p(int p, int& it, int& jt) {
    it = (int)((sqrtf(8.f * (float)p + 1.f) - 1.f) * 0.5f);
    while ((it + 1) * (it + 2) / 2 <= p) ++it;
    while (it * (it + 1) / 2 > p) --it;
    jt = p - it * (it + 1) / 2;
}

// ---------------------------------------------------------------------------
// Kernel 2a: per-(pair, column) partial softmax stats (m, d), bf16.
// ---------------------------------------------------------------------------
__global__ __launch_bounds__(256) void stats1_kernel(
    const u16* __restrict__ Khi, const u16* __restrict__ Klo,
    const u16* __restrict__ Qhi, const u16* __restrict__ Qlo,
    u16* __restrict__ Pm, u16* __restrict__ Pd)
{
    __shared__ u16 Abuf[8192], Bbuf[8192];
    __shared__ float redm[2][128], redd[2][128];

    const int tid = threadIdx.x, l = tid & 63, w = tid >> 6;
    const int wm = w & 1, wn = w >> 1;
    const int b = blockIdx.y;
    int it, jt; pair_from_p(blockIdx.x, it, jt);
    const long base = (long)b * Tn * HSn;

    f32x4 acc[4][4];
    score_tile_mfma(Khi, Klo, Qhi, Qlo, base, it * 128, jt * 128, Abuf, Bbuf, acc, tid);

    const int rquad = (l >> 4) * 4, col = l & 15;
    #pragma unroll
    for (int nt = 0; nt < 4; ++nt) {
        const int j = jt * 128 + wn * 64 + nt * 16 + col;
        float m = NEG_BIG;
        #pragma unroll
        for (int mt = 0; mt < 4; ++mt)
            #pragma unroll
            for (int r = 0; r < 4; ++r) {
                const int i = it * 128 + wm * 64 + mt * 16 + rquad + r;
                const float sv = (i >= j) ? acc[mt][nt][r] * SCALE : NEG_BIG;
                acc[mt][nt][r] = sv;
                m = fmaxf(m, sv);
            }
        m = fmaxf(m, __shfl_xor(m, 16));
        m = fmaxf(m, __shfl_xor(m, 32));
        float d = 0.f;
        #pragma unroll
        for (int mt = 0; mt < 4; ++mt)
            #pragma unroll
            for (int r = 0; r < 4; ++r)
                d += __expf(acc[mt][nt][r] - m);
        d += __shfl_xor(d, 16);
        d += __shfl_xor(d, 32);
        if (l < 16) {
            redm[wm][wn * 64 + nt * 16 + l] = m;
            redd[wm][wn * 64 + nt * 16 + l] = d;
        }
    }
    __syncthreads();
    if (tid < 128) {
        const float m0 = redm[0][tid], m1 = redm[1][tid];
        const float d0 = redd[0][tid], d1 = redd[1][tid];
        const float M = fmaxf(m0, m1);
        float D = d0 * __expf(m0 - M) + d1 * __expf(m1 - M);
        const float Mb = bf16_rn_f(M);
        D *= __expf(M - Mb);      // rebase to the rounded max we will store
        const long idx = ((long)b * NPAIR + blockIdx.x) * 128 + tid;
        Pm[idx] = (u16)(__float_as_uint(Mb) >> 16);
        Pd[idx] = bf16_rn(D);
    }
}

// ---------------------------------------------------------------------------
// Kernel 2b: merge partials over i-tiles -> Ms, Rd.
// ---------------------------------------------------------------------------
__global__ __launch_bounds__(128) void stats2_kernel(
    const u16* __restrict__ Pm, const u16* __restrict__ Pd,
    float* __restrict__ Ms, float* __restrict__ Rd)
{
    const int b = blockIdx.y, jt = blockIdx.x, jl = threadIdx.x;  // 128 threads
    float M = NEG_BIG, D = 0.f;
    for (int it = jt; it < NT; ++it) {
        const int p = it * (it + 1) / 2 + jt;
        const long idx = ((long)b * NPAIR + p) * 128 + jl;
        const float m = __uint_as_float((u32)Pm[idx] << 16);
        const float d = __uint_as_float((u32)Pd[idx] << 16);
        const float Mn = fmaxf(M, m);
        D = D * __expf(M - Mn) + d * __expf(m - Mn);
        M = Mn;
    }
    Ms[(long)b * Tn + jt * 128 + jl] = M;
    Rd[(long)b * Tn + jt * 128 + jl] = 1.f / D;
}

// ---------------------------------------------------------------------------
// Kernel 3: per-pair output partials (validated R3).
// ---------------------------------------------------------------------------
__global__ __launch_bounds__(256) void out_kernel(
    const u16* __restrict__ Khi, const u16* __restrict__ Klo,
    const u16* __restrict__ Qhi, const u16* __restrict__ Qlo,
    const u16* __restrict__ Vbf, const float* __restrict__ Ms,
    const float* __restrict__ Rd, float* __restrict__ Out)
{
    __shared__ u16 u_lds[34816];
    u16* Abuf = u_lds;
    u16* Bbuf = u_lds + 8192;
    u16* Pf   = u_lds;           // [128][136] bf16
    u16* Vt   = u_lds + 17408;   // [128][136] bf16 (h-major)

    const int tid = threadIdx.x, l = tid & 63, w = tid >> 6;
    const int wm = w & 1, wn = w >> 1;
    const int b = blockIdx.y;
    int it, jt; pair_from_p(blockIdx.x, it, jt);
    const long base = (long)b * Tn * HSn;

    f32x4 acc[4][4];
    score_tile_mfma(Khi, Klo, Qhi, Qlo, base, it * 128, jt * 128, Abuf, Bbuf, acc, tid);

    const int rquad = (l >> 4) * 4, col = l & 15;
    float mj[4], rj[4];
    #pragma unroll
    for (int nt = 0; nt < 4; ++nt) {
        const int j = jt * 128 + wn * 64 + nt * 16 + col;
        mj[nt] = Ms[(long)b * Tn + j];
        rj[nt] = Rd[(long)b * Tn + j];
    }
    #pragma unroll
    for (int nt = 0; nt < 4; ++nt) {
        const int j = jt * 128 + wn * 64 + nt * 16 + col;
        #pragma unroll
        for (int mt = 0; mt < 4; ++mt)
            #pragma unroll
            for (int r = 0; r < 4; ++r) {
                const int i = it * 128 + wm * 64 + mt * 16 + rquad + r;
                const float pv = (i >= j)
                    ? __expf(acc[mt][nt][r] * SCALE - mj[nt]) * rj[nt] : 0.f;
                Pf[(wm * 64 + mt * 16 + rquad + r) * 136 + wn * 64 + nt * 16 + col]
                    = bf16_rn(pv);
            }
    }

    const int lrow = l & 15, lk8 = (l >> 4) << 3;
    for (int ph = 0; ph < 2; ++ph) {
        __syncthreads();
        {
            const int jj = tid & 127, hs = (tid >> 7) * 64;
            const long vbase = ((long)b * Tn + jt * 128 + jj) * HSn + ph * 128 + hs;
            #pragma unroll
            for (int qq = 0; qq < 8; ++qq) {
                union { uint4 v; u16 s[8]; } uu;
                uu.v = *(const uint4*)(Vbf + vbase + qq * 8);
                #pragma unroll
                for (int e = 0; e < 8; ++e)
                    Vt[(hs + qq * 8 + e) * 136 + jj] = uu.s[e];
            }
        }
        __syncthreads();

        f32x4 o[4][4];
        #pragma unroll
        for (int a = 0; a < 4; ++a)
            #pragma unroll
            for (int bb = 0; bb < 4; ++bb)
                #pragma unroll
                for (int r = 0; r < 4; ++r) o[a][bb][r] = 0.f;

        #pragma unroll
        for (int kj = 0; kj < 4; ++kj) {
            bf16x8 aP[4];
            #pragma unroll
            for (int mt = 0; mt < 4; ++mt)
                aP[mt] = *(const bf16x8*)(Pf + (wm * 64 + mt * 16 + lrow) * 136 + kj * 32 + lk8);
            #pragma unroll
            for (int nt = 0; nt < 4; ++nt) {
                const bf16x8 bV = *(const bf16x8*)(Vt + (wn * 64 + nt * 16 + lrow) * 136 + kj * 32 + lk8);
                #pragma unroll
                for (int mt = 0; mt < 4; ++mt)
                    o[mt][nt] = __builtin_amdgcn_mfma_f32_16x16x32_bf16(aP[mt], bV, o[mt][nt], 0, 0, 0);
            }
        }
        #pragma unroll
        for (int mt = 0; mt < 4; ++mt)
            #pragma unroll
            for (int nt = 0; nt < 4; ++nt)
                #pragma unroll
                for (int r = 0; r < 4; ++r) {
                    const int i = it * 128 + wm * 64 + mt * 16 + rquad + r;
                    const int h = ph * 128 + wn * 64 + nt * 16 + col;
                    atomicAdd(&Out[((long)b * Tn + i) * HSn + h], o[mt][nt][r]);
                }
    }
}

extern "C" void kernel_launch(void* const* d_in, const int* in_sizes, int n_in,
                              void* d_out, int out_size, void* d_ws, size_t ws_size,
                              hipStream_t stream) {
    const float* X  = (const float*)d_in[0];
    const float* Wk = (const float*)d_in[1];
    const float* Wq = (const float*)d_in[2];
    const float* Wv = (const float*)d_in[3];

    const long nE = (long)Bn * Tn * HSn;          // 8,388,608 elements
    u16* Khi = (u16*)d_ws;
    u16* Klo = Khi + nE;
    u16* Qhi = Khi + 2 * nE;
    u16* Qlo = Khi + 3 * nE;
    u16* Vbf = Khi + 4 * nE;
    u16* Wt  = Khi + 5 * nE;                      // 6 arrays of WN (hi/lo x K,Q,V)
    u16* Pm  = Wt + 6L * WN;                      // [B][NPAIR][128] bf16
    u16* Pd  = Pm + (long)Bn * NPAIR * 128;
    float* Ms = (float*)(Pd + (long)Bn * NPAIR * 128);
    float* Rd = Ms + (long)Bn * Tn;
    // total ws ~= 91.5 MiB (< 96.6 MiB proven in R2)

    split_w_kernel<<<dim3(Cn, 3), 256, 0, stream>>>(Wk, Wq, Wv, Wt);
    projm_fused_kernel<<<dim3((Bn * Tn) / 64, HSn / 128), 256, 0, stream>>>(
        X, Wt, Khi, Klo, Qhi, Qlo, Vbf);
    stats1_kernel<<<dim3(NPAIR, Bn), 256, 0, stream>>>(Khi, Klo, Qhi, Qlo, Pm, Pd);
    stats2_kernel<<<dim3(NT, Bn), 128, 0, stream>>>(Pm, Pd, Ms, Rd);
    hipMemsetAsync(d_out, 0, (size_t)out_size * sizeof(float), stream);
    out_kernel<<<dim3(NPAIR, Bn), 256, 0, stream>>>(Khi, Klo, Qhi, Qlo, Vbf, Ms, Rd,
                                                    (float*)d_out);
}

// Round 4
// 1066.088 us; speedup vs baseline: 1.3378x; 1.0257x over previous
//
#include <hip/hip_runtime.h>
#include <math.h>

#define Bn 16
#define Tn 2048
#define Cn 2048
#define HSn 256
#define SCALE 45.254833995939045f
#define NEG_BIG (-1e30f)
#define NT 16          // number of 128-tiles along T
#define NPAIR 136      // NT*(NT+1)/2
#define WN 524288      // Cn*HSn, elems per W matrix

typedef __attribute__((ext_vector_type(8))) short bf16x8;
typedef __attribute__((ext_vector_type(4))) float f32x4;
typedef unsigned short u16;
typedef unsigned int u32;

__device__ __forceinline__ u16 bf16_rn(float f) {
    u32 u = __float_as_uint(f);
    u += 0x7fffu + ((u >> 16) & 1u);
    return (u16)(u >> 16);
}
__device__ __forceinline__ float bf16_rn_f(float f) {
    return __uint_as_float((u32)bf16_rn(f) << 16);
}

// async global->LDS, 16B per lane; LDS dst is wave-uniform base (+lane*16 implicit)
#define GLOAD_LDS16(gp, lp)                                                      \
    __builtin_amdgcn_global_load_lds(                                            \
        (const __attribute__((address_space(1))) unsigned int*)(gp),             \
        (__attribute__((address_space(3))) unsigned int*)(lp), 16, 0, 0)

#define WAITV0_LG0 asm volatile("s_waitcnt vmcnt(0) lgkmcnt(0)" ::: "memory")
#define WAITV2_LG0 asm volatile("s_waitcnt vmcnt(2) lgkmcnt(0)" ::: "memory")
#define WAITLG0    asm volatile("s_waitcnt lgkmcnt(0)" ::: "memory")
#define BARRIER    __builtin_amdgcn_s_barrier()

// ---------------------------------------------------------------------------
// Kernel 0: split W matrices into transposed bf16 hi/lo: Wt[mat][n][k].
// Order: KH(0) KL(1) QH(2) QL(3) VH(4) VL(5), each WN elems.
// ---------------------------------------------------------------------------
__global__ __launch_bounds__(256) void split_w_kernel(
    const float* __restrict__ Wk, const float* __restrict__ Wq,
    const float* __restrict__ Wv, u16* __restrict__ Wt)
{
    const int n = threadIdx.x, k = blockIdx.x, mat = blockIdx.y;
    const float* src = (mat == 0) ? Wk : (mat == 1) ? Wq : Wv;
    const float f = src[(long)k * HSn + n];
    const u32 u = __float_as_uint(f);
    const u16 hb = (u16)(u >> 16);                 // truncate -> hi
    const float fh = __uint_as_float(u & 0xffff0000u);
    const u16 lb = bf16_rn(f - fh);                // round residual -> lo
    u16* base = Wt + (long)mat * 2 * WN;
    base[(long)n * Cn + k] = hb;
    base[WN + (long)n * Cn + k] = lb;
}

// ---------------------------------------------------------------------------
// Kernel 1: FUSED K/Q/V projection, X-prefetch + raw barriers (counted vmcnt).
// Per half-k-step: issue W gloads (L2, drained at barrier1 via vmcnt(2)),
// prefetch next X half-tile (HBM, stays in flight across BOTH barriers),
// convert current X regs -> bf16 hi/lo -> LDS, MFMA. V is written TRANSPOSED
// (VbfT[b][h][j]) via an LDS bounce so out_kernel can stage it frag-native.
// ---------------------------------------------------------------------------
__global__ __launch_bounds__(256, 2) void projm_fused_kernel(
    const float* __restrict__ X, const u16* __restrict__ Wt,
    u16* __restrict__ Khi, u16* __restrict__ Klo,
    u16* __restrict__ Qhi, u16* __restrict__ Qlo, u16* __restrict__ VbfT)
{
    __shared__ u16 Ahi[2048], Alo[2048];   // 64x32 bf16, frag-native, 4 KB each
    __shared__ u16 Bbuf[20480];            // 5 halves x 8 chunks x 512, 40 KB

    const int tid = threadIdx.x, l = tid & 63, w = tid >> 6;
    const int wm = w & 1, wn = w >> 1;
    const int m0 = blockIdx.x * 64, n0 = blockIdx.y * 128;

    // --- X staging offsets: 2 float4 per thread covering 64x32 ---
    int xoff[2], aoff[2];
    #pragma unroll
    for (int p = 0; p < 2; ++p) {
        const int idx4 = p * 256 + tid;     // 0..511
        const int row  = idx4 >> 3;         // 0..63
        const int kk4  = (idx4 & 7) * 4;    // 0,4,...,28
        xoff[p] = (m0 + row) * Cn + kk4;
        aoff[p] = (row >> 4) * 512 + (((row & 15) | ((kk4 >> 3) << 4)) * 8) + (kk4 & 7);
    }

    // --- W staging: 40 chunks (5 halves x 8 n-chunks); wave w owns g=w*10+j ---
    int wgoff[10];
    const int lbase = w * 10 * 512;
    #pragma unroll
    for (int j = 0; j < 10; ++j) {
        const int g    = w * 10 + j;        // 0..39
        const int half = g >> 3;            // 0:KH 1:KL 2:QH 3:QL 4:VH
        const int cc   = g & 7;             // n-chunk
        const int nrow = n0 + cc * 16 + (l & 15);
        wgoff[j] = half * WN + nrow * Cn + ((l >> 4) << 3);
    }

    f32x4 accK[2][4], accQ[2][4], accV[2][4];
    #pragma unroll
    for (int mt = 0; mt < 2; ++mt)
        #pragma unroll
        for (int nt = 0; nt < 4; ++nt)
            #pragma unroll
            for (int r = 0; r < 4; ++r) {
                accK[mt][nt][r] = 0.f; accQ[mt][nt][r] = 0.f; accV[mt][nt][r] = 0.f;
            }

    float4 xA[2], xB[2];

    auto convert_write = [&](const float4 (&xr)[2]) {
        #pragma unroll
        for (int p = 0; p < 2; ++p) {
            const float xf[4] = {xr[p].x, xr[p].y, xr[p].z, xr[p].w};
            ushort4 h4, l4;
            #pragma unroll
            for (int c = 0; c < 4; ++c) {
                const u32 u = __float_as_uint(xf[c]);
                ((u16*)&h4)[c] = (u16)(u >> 16);
                const float fh = __uint_as_float(u & 0xffff0000u);
                ((u16*)&l4)[c] = bf16_rn(xf[c] - fh);
            }
            *(ushort4*)(Ahi + aoff[p]) = h4;
            *(ushort4*)(Alo + aoff[p]) = l4;
        }
    };

    auto mfma_all = [&]() {
        bf16x8 ah[2], al[2];
        #pragma unroll
        for (int mt = 0; mt < 2; ++mt) {
            ah[mt] = *(const bf16x8*)(Ahi + (wm * 2 + mt) * 512 + l * 8);
            al[mt] = *(const bf16x8*)(Alo + (wm * 2 + mt) * 512 + l * 8);
        }
        {   // K: 3-product
            bf16x8 bh[4], bl[4];
            #pragma unroll
            for (int nt = 0; nt < 4; ++nt) {
                bh[nt] = *(const bf16x8*)(Bbuf + (0 * 8 + wn * 4 + nt) * 512 + l * 8);
                bl[nt] = *(const bf16x8*)(Bbuf + (1 * 8 + wn * 4 + nt) * 512 + l * 8);
            }
            #pragma unroll
            for (int mt = 0; mt < 2; ++mt)
                #pragma unroll
                for (int nt = 0; nt < 4; ++nt) {
                    accK[mt][nt] = __builtin_amdgcn_mfma_f32_16x16x32_bf16(ah[mt], bh[nt], accK[mt][nt], 0, 0, 0);
                    accK[mt][nt] = __builtin_amdgcn_mfma_f32_16x16x32_bf16(ah[mt], bl[nt], accK[mt][nt], 0, 0, 0);
                    accK[mt][nt] = __builtin_amdgcn_mfma_f32_16x16x32_bf16(al[mt], bh[nt], accK[mt][nt], 0, 0, 0);
                }
        }
        {   // Q: 3-product
            bf16x8 bh[4], bl[4];
            #pragma unroll
            for (int nt = 0; nt < 4; ++nt) {
                bh[nt] = *(const bf16x8*)(Bbuf + (2 * 8 + wn * 4 + nt) * 512 + l * 8);
                bl[nt] = *(const bf16x8*)(Bbuf + (3 * 8 + wn * 4 + nt) * 512 + l * 8);
            }
            #pragma unroll
            for (int mt = 0; mt < 2; ++mt)
                #pragma unroll
                for (int nt = 0; nt < 4; ++nt) {
                    accQ[mt][nt] = __builtin_amdgcn_mfma_f32_16x16x32_bf16(ah[mt], bh[nt], accQ[mt][nt], 0, 0, 0);
                    accQ[mt][nt] = __builtin_amdgcn_mfma_f32_16x16x32_bf16(ah[mt], bl[nt], accQ[mt][nt], 0, 0, 0);
                    accQ[mt][nt] = __builtin_amdgcn_mfma_f32_16x16x32_bf16(al[mt], bh[nt], accQ[mt][nt], 0, 0, 0);
                }
        }
        {   // V: hi only
            bf16x8 bh[4];
            #pragma unroll
            for (int nt = 0; nt < 4; ++nt)
                bh[nt] = *(const bf16x8*)(Bbuf + (4 * 8 + wn * 4 + nt) * 512 + l * 8);
            #pragma unroll
            for (int mt = 0; mt < 2; ++mt)
                #pragma unroll
                for (int nt = 0; nt < 4; ++nt)
                    accV[mt][nt] = __builtin_amdgcn_mfma_f32_16x16x32_bf16(ah[mt], bh[nt], accV[mt][nt], 0, 0, 0);
        }
    };

    // prologue: X(0) in flight
    xA[0] = *(const float4*)(X + xoff[0]);
    xA[1] = *(const float4*)(X + xoff[1]);

    #pragma unroll 1
    for (int k0 = 0; k0 < Cn; k0 += 64) {
        // ---- half 1: consume xA(k0), prefetch xB(k0+32) ----
        #pragma unroll
        for (int j = 0; j < 10; ++j)
            GLOAD_LDS16(Wt + wgoff[j] + k0, Bbuf + lbase + j * 512);
        __builtin_amdgcn_sched_barrier(0);   // pin VMEM order: gloads before X loads
        xB[0] = *(const float4*)(X + xoff[0] + k0 + 32);
        xB[1] = *(const float4*)(X + xoff[1] + k0 + 32);
        convert_write(xA);                   // waits xA (vmcnt<=12), keeps gloads+xB
        WAITV2_LG0;                          // W staged + A visible; xB stays in flight
        BARRIER;
        mfma_all();
        WAITLG0;                             // frag reads retired
        BARRIER;
        // ---- half 2: consume xB(k0+32), prefetch xA(next, clamped) ----
        #pragma unroll
        for (int j = 0; j < 10; ++j)
            GLOAD_LDS16(Wt + wgoff[j] + k0 + 32, Bbuf + lbase + j * 512);
        __builtin_amdgcn_sched_barrier(0);
        const int kn = (k0 + 64 < Cn) ? k0 + 64 : 0;   // always 2 X loads in flight
        xA[0] = *(const float4*)(X + xoff[0] + kn);
        xA[1] = *(const float4*)(X + xoff[1] + kn);
        convert_write(xB);
        WAITV2_LG0;
        BARRIER;
        mfma_all();
        WAITLG0;
        BARRIER;
    }

    // --- epilogue: C/D layout col=l&15, row=(l>>4)*4+r ---
    const int quad = (l >> 4) * 4, col = l & 15;
    u16* Vlds = Bbuf;                       // alias: 64x128 bounce (16 KB of 40)
    #pragma unroll
    for (int mt = 0; mt < 2; ++mt)
        #pragma unroll
        for (int nt = 0; nt < 4; ++nt)
            #pragma unroll
            for (int r = 0; r < 4; ++r) {
                const long i = m0 + wm * 32 + mt * 16 + quad + r;
                const int  j = n0 + wn * 64 + nt * 16 + col;
                {   // K hi/lo
                    const float f = accK[mt][nt][r];
                    const u32 u = __float_as_uint(f);
                    Khi[i * HSn + j] = (u16)(u >> 16);
                    const float fh = __uint_as_float(u & 0xffff0000u);
                    Klo[i * HSn + j] = bf16_rn(f - fh);
                }
                {   // Q hi/lo
                    const float f = accQ[mt][nt][r];
                    const u32 u = __float_as_uint(f);
                    Qhi[i * HSn + j] = (u16)(u >> 16);
                    const float fh = __uint_as_float(u & 0xffff0000u);
                    Qlo[i * HSn + j] = bf16_rn(f - fh);
                }
                Vlds[(wm * 32 + mt * 16 + quad + r) * 128 + wn * 64 + nt * 16 + col]
                    = bf16_rn(accV[mt][nt][r]);
            }
    __syncthreads();
    // transposed V write: VbfT[b][h][j], 128B-contiguous per h-row
    // FIX(R4): hl is the LOCAL column (LDS index); global h = n0 + hl.
    {
        const int bidx = m0 >> 11, jb = m0 & (Tn - 1);
        #pragma unroll
        for (int hh = 0; hh < 4; ++hh) {
            const int hl = hh * 32 + (tid >> 3);     // local col 0..127
            const int h  = n0 + hl;                  // global head index
            const int jl = (tid & 7) * 8;
            union { uint4 v; u16 s[8]; } pk;
            #pragma unroll
            for (int e = 0; e < 8; ++e) pk.s[e] = Vlds[(jl + e) * 128 + hl];
            *(uint4*)(VbfT + ((long)bidx * HSn + h) * Tn + jb + jl) = pk.v;
        }
    }
}

// ---------------------------------------------------------------------------
// Shared: 128x128 score tile, gload_lds staging + LDS double-buffer +
// counted-vmcnt pipeline (T3 minimal 2-phase). Numerics identical to R2.
// Buffers: Ab0/Bb0/Ab1/Bb1, 8192 u16 each.
// ---------------------------------------------------------------------------
__device__ __forceinline__ void score_tile_mfma(
    const u16* __restrict__ Khi, const u16* __restrict__ Klo,
    const u16* __restrict__ Qhi, const u16* __restrict__ Qlo,
    long base, int i0, int j0,
    u16* Ab0, u16* Bb0, u16* Ab1, u16* Bb1,
    f32x4 (&acc)[4][4], int tid)
{
    const int l = tid & 63, w = tid >> 6;
    const int wm = w & 1, wn = w >> 1;
    const int lrow = l & 15, lk8 = (l >> 4) << 3;

    #pragma unroll
    for (int a = 0; a < 4; ++a)
        #pragma unroll
        for (int bb = 0; bb < 4; ++bb)
            #pragma unroll
            for (int r = 0; r < 4; ++r) acc[a][bb][r] = 0.f;

    // wave 0,1 stage A(K); wave 2,3 stage B(Q). chunk c = (w&1)*8+q, half=q&1
    const u16* hiP = wn ? Qhi : Khi;
    const u16* loP = wn ? Qlo : Klo;
    const int  t0  = wn ? j0 : i0;
    long rowoff[4];
    #pragma unroll
    for (int m2 = 0; m2 < 4; ++m2) {
        const int mt = (w & 1) * 4 + m2;
        rowoff[m2] = base + (long)(t0 + mt * 16 + lrow) * HSn + lk8;
    }
    u16* dst0 = (wn ? Bb0 : Ab0) + (w & 1) * 8 * 512;
    u16* dst1 = (wn ? Bb1 : Ab1) + (w & 1) * 8 * 512;

    auto stage = [&](int h0, u16* dw) {
        #pragma unroll
        for (int q = 0; q < 8; ++q) {
            const u16* sp = (q & 1) ? loP : hiP;
            GLOAD_LDS16(sp + rowoff[q >> 1] + h0, dw + q * 512);
        }
    };
    auto step = [&](const u16* Ab, const u16* Bb) {
        bf16x8 bh[4], bl[4];
        #pragma unroll
        for (int nt = 0; nt < 4; ++nt) {
            const int c2 = (wn * 4 + nt) * 2;
            bh[nt] = *(const bf16x8*)(Bb + (c2    ) * 512 + l * 8);
            bl[nt] = *(const bf16x8*)(Bb + (c2 + 1) * 512 + l * 8);
        }
        #pragma unroll
        for (int mt = 0; mt < 4; ++mt) {
            const int c2 = (wm * 4 + mt) * 2;
            const bf16x8 ah = *(const bf16x8*)(Ab + (c2    ) * 512 + l * 8);
            const bf16x8 al = *(const bf16x8*)(Ab + (c2 + 1) * 512 + l * 8);
            #pragma unroll
            for (int nt = 0; nt < 4; ++nt) {
                acc[mt][nt] = __builtin_amdgcn_mfma_f32_16x16x32_bf16(ah, bh[nt], acc[mt][nt], 0, 0, 0);
                acc[mt][nt] = __builtin_amdgcn_mfma_f32_16x16x32_bf16(ah, bl[nt], acc[mt][nt], 0, 0, 0);
                acc[mt][nt] = __builtin_amdgcn_mfma_f32_16x16x32_bf16(al, bh[nt], acc[mt][nt], 0, 0, 0);
            }
        }
    };

    stage(0, dst0);
    WAITV0_LG0;
    BARRIER;
    #pragma unroll 1
    for (int ks = 0; ks < 8; ks += 2) {
        stage((ks + 1) * 32, dst1);          // prefetch odd step
        step(Ab0, Bb0);
        WAITV0_LG0;                          // prefetch landed + reads retired
        BARRIER;
        if (ks + 2 < 8) stage((ks + 2) * 32, dst0);
        step(Ab1, Bb1);
        WAITV0_LG0;
        BARRIER;
    }
}

__device__ __forceinline__ void pair_from_p(int p, int& it, int& jt) {
    it = (int)((sqrtf(8.f * (float)p + 1.f) - 1.f) * 0.5f);
    while ((it + 1) * (it + 2) / 2 <= p) ++it;
    while (it * (it + 1) / 2 > p) --it;
    jt = p - it * (it + 1) / 2;
}

// ---------------------------------------------------------------------------
// Kernel 2a: per-(pair, column) partial softmax stats (m, d), bf16.
// ---------------------------------------------------------------------------
__global__ __launch_bounds__(256) void stats1_kernel(
    const u16* __restrict__ Khi, const u16* __restrict__ Klo,
    const u16* __restrict__ Qhi, const u16* __restrict__ Qlo,
    u16* __restrict__ Pm, u16* __restrict__ Pd)
{
    __shared__ u16 s_lds[32768];           // 2x(A+B) buffers, 64 KB
    __shared__ float redm[2][128], redd[2][128];

    const int tid = threadIdx.x, l = tid & 63, w = tid >> 6;
    const int wm = w & 1, wn = w >> 1;
    const int b = blockIdx.y;
    int it, jt; pair_from_p(blockIdx.x, it, jt);
    const long base = (long)b * Tn * HSn;

    f32x4 acc[4][4];
    score_tile_mfma(Khi, Klo, Qhi, Qlo, base, it * 128, jt * 128,
                    s_lds, s_lds + 8192, s_lds + 16384, s_lds + 24576, acc, tid);

    const int rquad = (l >> 4) * 4, col = l & 15;
    #pragma unroll
    for (int nt = 0; nt < 4; ++nt) {
        const int j = jt * 128 + wn * 64 + nt * 16 + col;
        float m = NEG_BIG;
        #pragma unroll
        for (int mt = 0; mt < 4; ++mt)
            #pragma unroll
            for (int r = 0; r < 4; ++r) {
                const int i = it * 128 + wm * 64 + mt * 16 + rquad + r;
                const float sv = (i >= j) ? acc[mt][nt][r] * SCALE : NEG_BIG;
                acc[mt][nt][r] = sv;
                m = fmaxf(m, sv);
            }
        m = fmaxf(m, __shfl_xor(m, 16));
        m = fmaxf(m, __shfl_xor(m, 32));
        float d = 0.f;
        #pragma unroll
        for (int mt = 0; mt < 4; ++mt)
            #pragma unroll
            for (int r = 0; r < 4; ++r)
                d += __expf(acc[mt][nt][r] - m);
        d += __shfl_xor(d, 16);
        d += __shfl_xor(d, 32);
        if (l < 16) {
            redm[wm][wn * 64 + nt * 16 + l] = m;
            redd[wm][wn * 64 + nt * 16 + l] = d;
        }
    }
    __syncthreads();
    if (tid < 128) {
        const float m0 = redm[0][tid], m1 = redm[1][tid];
        const float d0 = redd[0][tid], d1 = redd[1][tid];
        const float M = fmaxf(m0, m1);
        float D = d0 * __expf(m0 - M) + d1 * __expf(m1 - M);
        const float Mb = bf16_rn_f(M);
        D *= __expf(M - Mb);      // rebase to the rounded max we will store
        const long idx = ((long)b * NPAIR + blockIdx.x) * 128 + tid;
        Pm[idx] = (u16)(__float_as_uint(Mb) >> 16);
        Pd[idx] = bf16_rn(D);
    }
}

// ---------------------------------------------------------------------------
// Kernel 2b: merge partials over i-tiles -> Ms, Rd.
// ---------------------------------------------------------------------------
__global__ __launch_bounds__(128) void stats2_kernel(
    const u16* __restrict__ Pm, const u16* __restrict__ Pd,
    float* __restrict__ Ms, float* __restrict__ Rd)
{
    const int b = blockIdx.y, jt = blockIdx.x, jl = threadIdx.x;  // 128 threads
    float M = NEG_BIG, D = 0.f;
    for (int it = jt; it < NT; ++it) {
        const int p = it * (it + 1) / 2 + jt;
        const long idx = ((long)b * NPAIR + p) * 128 + jl;
        const float m = __uint_as_float((u32)Pm[idx] << 16);
        const float d = __uint_as_float((u32)Pd[idx] << 16);
        const float Mn = fmaxf(M, m);
        D = D * __expf(M - Mn) + d * __expf(m - Mn);
        M = Mn;
    }
    Ms[(long)b * Tn + jt * 128 + jl] = M;
    Rd[(long)b * Tn + jt * 128 + jl] = 1.f / D;
}

// ---------------------------------------------------------------------------
// Kernel 3: per-pair output partials. V staged frag-native from VbfT via
// gload_lds (transpose moved to projm); Pf unchanged.
// ---------------------------------------------------------------------------
__global__ __launch_bounds__(256) void out_kernel(
    const u16* __restrict__ Khi, const u16* __restrict__ Klo,
    const u16* __restrict__ Qhi, const u16* __restrict__ Qlo,
    const u16* __restrict__ VbfT, const float* __restrict__ Ms,
    const float* __restrict__ Rd, float* __restrict__ Out)
{
    __shared__ u16 u_lds[33792];   // 66 KB: score 2x(A+B)=64 KB | Pf 34 KB + Vfrag 32 KB
    u16* Pf    = u_lds;            // [128][136] bf16
    u16* Vfrag = u_lds + 17408;    // 32 chunks x 512 = 32 KB, layout [kj][hg]

    const int tid = threadIdx.x, l = tid & 63, w = tid >> 6;
    const int wm = w & 1, wn = w >> 1;
    const int lrow = l & 15, lk8 = (l >> 4) << 3;
    const int b = blockIdx.y;
    int it, jt; pair_from_p(blockIdx.x, it, jt);
    const long base = (long)b * Tn * HSn;

    f32x4 acc[4][4];
    score_tile_mfma(Khi, Klo, Qhi, Qlo, base, it * 128, jt * 128,
                    u_lds, u_lds + 8192, u_lds + 16384, u_lds + 24576, acc, tid);

    // wave w stages kj=w, h-group q (16 h x 32 j per chunk)
    auto stage_v = [&](int ph) {
        #pragma unroll
        for (int q = 0; q < 8; ++q) {
            const int hh = ph * 128 + q * 16 + lrow;
            const long ga = ((long)b * HSn + hh) * Tn + jt * 128 + w * 32 + lk8;
            GLOAD_LDS16(VbfT + ga, Vfrag + (w * 8 + q) * 512);
        }
    };

    stage_v(0);   // in flight under Pf computation; drained by next __syncthreads

    const int rquad = (l >> 4) * 4, col = l & 15;
    float mj[4], rj[4];
    #pragma unroll
    for (int nt = 0; nt < 4; ++nt) {
        const int j = jt * 128 + wn * 64 + nt * 16 + col;
        mj[nt] = Ms[(long)b * Tn + j];
        rj[nt] = Rd[(long)b * Tn + j];
    }
    #pragma unroll
    for (int nt = 0; nt < 4; ++nt) {
        const int j = jt * 128 + wn * 64 + nt * 16 + col;
        #pragma unroll
        for (int mt = 0; mt < 4; ++mt)
            #pragma unroll
            for (int r = 0; r < 4; ++r) {
                const int i = it * 128 + wm * 64 + mt * 16 + rquad + r;
                const float pv = (i >= j)
                    ? __expf(acc[mt][nt][r] * SCALE - mj[nt]) * rj[nt] : 0.f;
                Pf[(wm * 64 + mt * 16 + rquad + r) * 136 + wn * 64 + nt * 16 + col]
                    = bf16_rn(pv);
            }
    }

    auto pv_store = [&](int ph) {
        f32x4 o[4][4];
        #pragma unroll
        for (int a = 0; a < 4; ++a)
            #pragma unroll
            for (int bb = 0; bb < 4; ++bb)
                #pragma unroll
                for (int r = 0; r < 4; ++r) o[a][bb][r] = 0.f;
        #pragma unroll
        for (int kj = 0; kj < 4; ++kj) {
            bf16x8 aP[4];
            #pragma unroll
            for (int mt = 0; mt < 4; ++mt)
                aP[mt] = *(const bf16x8*)(Pf + (wm * 64 + mt * 16 + lrow) * 136 + kj * 32 + lk8);
            #pragma unroll
            for (int nt = 0; nt < 4; ++nt) {
                const bf16x8 bV = *(const bf16x8*)(Vfrag + (kj * 8 + wn * 4 + nt) * 512 + l * 8);
                #pragma unroll
                for (int mt = 0; mt < 4; ++mt)
                    o[mt][nt] = __builtin_amdgcn_mfma_f32_16x16x32_bf16(aP[mt], bV, o[mt][nt], 0, 0, 0);
            }
        }
        #pragma unroll
        for (int mt = 0; mt < 4; ++mt)
            #pragma unroll
            for (int nt = 0; nt < 4; ++nt)
                #pragma unroll
                for (int r = 0; r < 4; ++r) {
                    const int i = it * 128 + wm * 64 + mt * 16 + rquad + r;
                    const int h = ph * 128 + wn * 64 + nt * 16 + col;
                    atomicAdd(&Out[((long)b * Tn + i) * HSn + h], o[mt][nt][r]);
                }
    };

    __syncthreads();      // Pf visible + V(ph=0) staged (full drain)
    pv_store(0);
    __syncthreads();      // PV(0) Vfrag reads retired
    stage_v(1);
    __syncthreads();      // V(ph=1) staged
    pv_store(1);
}

extern "C" void kernel_launch(void* const* d_in, const int* in_sizes, int n_in,
                              void* d_out, int out_size, void* d_ws, size_t ws_size,
                              hipStream_t stream) {
    const float* X  = (const float*)d_in[0];
    const float* Wk = (const float*)d_in[1];
    const float* Wq = (const float*)d_in[2];
    const float* Wv = (const float*)d_in[3];

    const long nE = (long)Bn * Tn * HSn;          // 8,388,608 elements
    u16* Khi = (u16*)d_ws;
    u16* Klo = Khi + nE;
    u16* Qhi = Khi + 2 * nE;
    u16* Qlo = Khi + 3 * nE;
    u16* VbfT = Khi + 4 * nE;                     // [b][h][j] transposed bf16 V
    u16* Wt  = Khi + 5 * nE;                      // 6 arrays of WN (hi/lo x K,Q,V)
    u16* Pm  = Wt + 6L * WN;                      // [B][NPAIR][128] bf16
    u16* Pd  = Pm + (long)Bn * NPAIR * 128;
    float* Ms = (float*)(Pd + (long)Bn * NPAIR * 128);
    float* Rd = Ms + (long)Bn * Tn;

    split_w_kernel<<<dim3(Cn, 3), 256, 0, stream>>>(Wk, Wq, Wv, Wt);
    projm_fused_kernel<<<dim3((Bn * Tn) / 64, HSn / 128), 256, 0, stream>>>(
        X, Wt, Khi, Klo, Qhi, Qlo, VbfT);
    stats1_kernel<<<dim3(NPAIR, Bn), 256, 0, stream>>>(Khi, Klo, Qhi, Qlo, Pm, Pd);
    stats2_kernel<<<dim3(NT, Bn), 128, 0, stream>>>(Pm, Pd, Ms, Rd);
    hipMemsetAsync(d_out, 0, (size_t)out_size * sizeof(float), stream);
    out_kernel<<<dim3(NPAIR, Bn), 256, 0, stream>>>(Khi, Klo, Qhi, Qlo, VbfT, Ms, Rd,
                                                    (float*)d_out);
}

// Round 5
// 1004.856 us; speedup vs baseline: 1.4193x; 1.0609x over previous
//
#include <hip/hip_runtime.h>
#include <math.h>

#define Bn 16
#define Tn 2048
#define Cn 2048
#define HSn 256
#define SCALE 45.254833995939045f
#define NEG_BIG (-1e30f)
#define NT 16          // number of 128-tiles along T
#define NPAIR 136      // NT*(NT+1)/2
#define WN 524288      // Cn*HSn, elems per W matrix

typedef __attribute__((ext_vector_type(8))) short bf16x8;
typedef __attribute__((ext_vector_type(4))) float f32x4;
typedef unsigned short u16;
typedef unsigned int u32;

__device__ __forceinline__ u16 bf16_rn(float f) {
    u32 u = __float_as_uint(f);
    u += 0x7fffu + ((u >> 16) & 1u);
    return (u16)(u >> 16);
}
__device__ __forceinline__ float bf16_rn_f(float f) {
    return __uint_as_float((u32)bf16_rn(f) << 16);
}

// async global->LDS, 16B per lane; LDS dst is wave-uniform base (+lane*16 implicit)
#define GLOAD_LDS16(gp, lp)                                                      \
    __builtin_amdgcn_global_load_lds(                                            \
        (const __attribute__((address_space(1))) unsigned int*)(gp),             \
        (__attribute__((address_space(3))) unsigned int*)(lp), 16, 0, 0)

#define WAITV0_LG0 asm volatile("s_waitcnt vmcnt(0) lgkmcnt(0)" ::: "memory")
#define WAITV2_LG0 asm volatile("s_waitcnt vmcnt(2) lgkmcnt(0)" ::: "memory")
#define WAITLG0    asm volatile("s_waitcnt lgkmcnt(0)" ::: "memory")
#define BARRIER    __builtin_amdgcn_s_barrier()

// ---------------------------------------------------------------------------
// Kernel 0: split W matrices into transposed bf16 hi/lo: Wt[mat][n][k].
// Order: KH(0) KL(1) QH(2) QL(3) VH(4) VL(5), each WN elems.
// ---------------------------------------------------------------------------
__global__ __launch_bounds__(256) void split_w_kernel(
    const float* __restrict__ Wk, const float* __restrict__ Wq,
    const float* __restrict__ Wv, u16* __restrict__ Wt)
{
    const int n = threadIdx.x, k = blockIdx.x, mat = blockIdx.y;
    const float* src = (mat == 0) ? Wk : (mat == 1) ? Wq : Wv;
    const float f = src[(long)k * HSn + n];
    const u32 u = __float_as_uint(f);
    const u16 hb = (u16)(u >> 16);                 // truncate -> hi
    const float fh = __uint_as_float(u & 0xffff0000u);
    const u16 lb = bf16_rn(f - fh);                // round residual -> lo
    u16* base = Wt + (long)mat * 2 * WN;
    base[(long)n * Cn + k] = hb;
    base[WN + (long)n * Cn + k] = lb;
}

// ---------------------------------------------------------------------------
// Kernel 1: FUSED K/Q/V projection — 128x128 tile, 8 waves (512 threads).
// Per-wave work/accumulator layout identical to R4 (32m x 64n, 2x4 frags),
// so numerics are bit-identical; only geometry/occupancy changes:
// 16 waves/CU (4/SIMD) vs 8 (2/SIMD). W staging 5 gloads/wave.
// ---------------------------------------------------------------------------
__global__ __launch_bounds__(512, 2) void projm_fused_kernel(
    const float* __restrict__ X, const u16* __restrict__ Wt,
    u16* __restrict__ Khi, u16* __restrict__ Klo,
    u16* __restrict__ Qhi, u16* __restrict__ Qlo, u16* __restrict__ VbfT)
{
    __shared__ u16 Ahi[4096], Alo[4096];   // 128x32 bf16, frag-native, 8 KB each
    __shared__ u16 Bbuf[20480];            // 5 halves x 8 chunks x 512, 40 KB

    const int tid = threadIdx.x, l = tid & 63, w = tid >> 6;   // w in 0..7
    const int wm = w & 3, wn = w >> 2;     // 4 m-quadrants x 2 n-halves
    const int m0 = blockIdx.x * 128, n0 = blockIdx.y * 128;

    // --- X staging offsets: 2 float4 per thread covering 128x32 ---
    int xoff[2], aoff[2];
    #pragma unroll
    for (int p = 0; p < 2; ++p) {
        const int idx4 = p * 512 + tid;     // 0..1023
        const int row  = idx4 >> 3;         // 0..127
        const int kk4  = (idx4 & 7) * 4;    // 0,4,...,28
        xoff[p] = (m0 + row) * Cn + kk4;
        aoff[p] = (row >> 4) * 512 + (((row & 15) | ((kk4 >> 3) << 4)) * 8) + (kk4 & 7);
    }

    // --- W staging: 40 chunks (5 halves x 8 n-chunks); wave w owns g=w*5+j ---
    int wgoff[5];
    const int lbase = w * 5 * 512;          // == g*512 for j=0
    #pragma unroll
    for (int j = 0; j < 5; ++j) {
        const int g    = w * 5 + j;         // 0..39 ; chunk index = half*8+cc = g
        const int half = g >> 3;            // 0:KH 1:KL 2:QH 3:QL 4:VH
        const int cc   = g & 7;             // n-chunk
        const int nrow = n0 + cc * 16 + (l & 15);
        wgoff[j] = half * WN + nrow * Cn + ((l >> 4) << 3);
    }

    f32x4 accK[2][4], accQ[2][4], accV[2][4];
    #pragma unroll
    for (int mt = 0; mt < 2; ++mt)
        #pragma unroll
        for (int nt = 0; nt < 4; ++nt)
            #pragma unroll
            for (int r = 0; r < 4; ++r) {
                accK[mt][nt][r] = 0.f; accQ[mt][nt][r] = 0.f; accV[mt][nt][r] = 0.f;
            }

    float4 xA[2], xB[2];

    auto convert_write = [&](const float4 (&xr)[2]) {
        #pragma unroll
        for (int p = 0; p < 2; ++p) {
            const float xf[4] = {xr[p].x, xr[p].y, xr[p].z, xr[p].w};
            ushort4 h4, l4;
            #pragma unroll
            for (int c = 0; c < 4; ++c) {
                const u32 u = __float_as_uint(xf[c]);
                ((u16*)&h4)[c] = (u16)(u >> 16);
                const float fh = __uint_as_float(u & 0xffff0000u);
                ((u16*)&l4)[c] = bf16_rn(xf[c] - fh);
            }
            *(ushort4*)(Ahi + aoff[p]) = h4;
            *(ushort4*)(Alo + aoff[p]) = l4;
        }
    };

    auto mfma_all = [&]() {
        bf16x8 ah[2], al[2];
        #pragma unroll
        for (int mt = 0; mt < 2; ++mt) {
            ah[mt] = *(const bf16x8*)(Ahi + (wm * 2 + mt) * 512 + l * 8);
            al[mt] = *(const bf16x8*)(Alo + (wm * 2 + mt) * 512 + l * 8);
        }
        {   // K: 3-product
            bf16x8 bh[4], bl[4];
            #pragma unroll
            for (int nt = 0; nt < 4; ++nt) {
                bh[nt] = *(const bf16x8*)(Bbuf + (0 * 8 + wn * 4 + nt) * 512 + l * 8);
                bl[nt] = *(const bf16x8*)(Bbuf + (1 * 8 + wn * 4 + nt) * 512 + l * 8);
            }
            #pragma unroll
            for (int mt = 0; mt < 2; ++mt)
                #pragma unroll
                for (int nt = 0; nt < 4; ++nt) {
                    accK[mt][nt] = __builtin_amdgcn_mfma_f32_16x16x32_bf16(ah[mt], bh[nt], accK[mt][nt], 0, 0, 0);
                    accK[mt][nt] = __builtin_amdgcn_mfma_f32_16x16x32_bf16(ah[mt], bl[nt], accK[mt][nt], 0, 0, 0);
                    accK[mt][nt] = __builtin_amdgcn_mfma_f32_16x16x32_bf16(al[mt], bh[nt], accK[mt][nt], 0, 0, 0);
                }
        }
        {   // Q: 3-product
            bf16x8 bh[4], bl[4];
            #pragma unroll
            for (int nt = 0; nt < 4; ++nt) {
                bh[nt] = *(const bf16x8*)(Bbuf + (2 * 8 + wn * 4 + nt) * 512 + l * 8);
                bl[nt] = *(const bf16x8*)(Bbuf + (3 * 8 + wn * 4 + nt) * 512 + l * 8);
            }
            #pragma unroll
            for (int mt = 0; mt < 2; ++mt)
                #pragma unroll
                for (int nt = 0; nt < 4; ++nt) {
                    accQ[mt][nt] = __builtin_amdgcn_mfma_f32_16x16x32_bf16(ah[mt], bh[nt], accQ[mt][nt], 0, 0, 0);
                    accQ[mt][nt] = __builtin_amdgcn_mfma_f32_16x16x32_bf16(ah[mt], bl[nt], accQ[mt][nt], 0, 0, 0);
                    accQ[mt][nt] = __builtin_amdgcn_mfma_f32_16x16x32_bf16(al[mt], bh[nt], accQ[mt][nt], 0, 0, 0);
                }
        }
        {   // V: hi only
            bf16x8 bh[4];
            #pragma unroll
            for (int nt = 0; nt < 4; ++nt)
                bh[nt] = *(const bf16x8*)(Bbuf + (4 * 8 + wn * 4 + nt) * 512 + l * 8);
            #pragma unroll
            for (int mt = 0; mt < 2; ++mt)
                #pragma unroll
                for (int nt = 0; nt < 4; ++nt)
                    accV[mt][nt] = __builtin_amdgcn_mfma_f32_16x16x32_bf16(ah[mt], bh[nt], accV[mt][nt], 0, 0, 0);
        }
    };

    // prologue: X(0) in flight
    xA[0] = *(const float4*)(X + xoff[0]);
    xA[1] = *(const float4*)(X + xoff[1]);

    #pragma unroll 1
    for (int k0 = 0; k0 < Cn; k0 += 64) {
        // ---- half 1: consume xA(k0), prefetch xB(k0+32) ----
        #pragma unroll
        for (int j = 0; j < 5; ++j)
            GLOAD_LDS16(Wt + wgoff[j] + k0, Bbuf + lbase + j * 512);
        __builtin_amdgcn_sched_barrier(0);   // pin VMEM order: gloads before X loads
        xB[0] = *(const float4*)(X + xoff[0] + k0 + 32);
        xB[1] = *(const float4*)(X + xoff[1] + k0 + 32);
        convert_write(xA);                   // xA already in regs; keeps gloads+xB in flight
        WAITV2_LG0;                          // W staged + A visible; xB stays in flight
        BARRIER;
        mfma_all();
        WAITLG0;                             // frag reads retired
        BARRIER;
        // ---- half 2: consume xB(k0+32), prefetch xA(next, clamped) ----
        #pragma unroll
        for (int j = 0; j < 5; ++j)
            GLOAD_LDS16(Wt + wgoff[j] + k0 + 32, Bbuf + lbase + j * 512);
        __builtin_amdgcn_sched_barrier(0);
        const int kn = (k0 + 64 < Cn) ? k0 + 64 : 0;   // always 2 X loads in flight
        xA[0] = *(const float4*)(X + xoff[0] + kn);
        xA[1] = *(const float4*)(X + xoff[1] + kn);
        convert_write(xB);
        WAITV2_LG0;
        BARRIER;
        mfma_all();
        WAITLG0;
        BARRIER;
    }

    // --- epilogue: C/D layout col=l&15, row=(l>>4)*4+r ---
    const int quad = (l >> 4) * 4, col = l & 15;
    u16* Vlds = Bbuf;                       // alias: 128x128 bounce (32 KB of 40)
    #pragma unroll
    for (int mt = 0; mt < 2; ++mt)
        #pragma unroll
        for (int nt = 0; nt < 4; ++nt)
            #pragma unroll
            for (int r = 0; r < 4; ++r) {
                const long i = m0 + wm * 32 + mt * 16 + quad + r;
                const int  j = n0 + wn * 64 + nt * 16 + col;
                {   // K hi/lo
                    const float f = accK[mt][nt][r];
                    const u32 u = __float_as_uint(f);
                    Khi[i * HSn + j] = (u16)(u >> 16);
                    const float fh = __uint_as_float(u & 0xffff0000u);
                    Klo[i * HSn + j] = bf16_rn(f - fh);
                }
                {   // Q hi/lo
                    const float f = accQ[mt][nt][r];
                    const u32 u = __float_as_uint(f);
                    Qhi[i * HSn + j] = (u16)(u >> 16);
                    const float fh = __uint_as_float(u & 0xffff0000u);
                    Qlo[i * HSn + j] = bf16_rn(f - fh);
                }
                Vlds[(wm * 32 + mt * 16 + quad + r) * 128 + wn * 64 + nt * 16 + col]
                    = bf16_rn(accV[mt][nt][r]);
            }
    __syncthreads();
    // transposed V write: VbfT[b][h][j]; hl = LOCAL col (LDS), global h = n0+hl
    {
        const int bidx = m0 >> 11, jb = m0 & (Tn - 1);
        #pragma unroll
        for (int hh = 0; hh < 4; ++hh) {
            const int hl = hh * 32 + (tid >> 4);     // local col 0..127
            const int h  = n0 + hl;                  // global head index
            const int jl = (tid & 15) * 8;           // local j 0..120
            union { uint4 v; u16 s[8]; } pk;
            #pragma unroll
            for (int e = 0; e < 8; ++e) pk.s[e] = Vlds[(jl + e) * 128 + hl];
            *(uint4*)(VbfT + ((long)bidx * HSn + h) * Tn + jb + jl) = pk.v;
        }
    }
}

// ---------------------------------------------------------------------------
// Shared: 128x128 score tile, gload_lds staging + LDS double-buffer +
// counted-vmcnt pipeline (T3 minimal 2-phase). Numerics identical to R2.
// Buffers: Ab0/Bb0/Ab1/Bb1, 8192 u16 each.
// ---------------------------------------------------------------------------
__device__ __forceinline__ void score_tile_mfma(
    const u16* __restrict__ Khi, const u16* __restrict__ Klo,
    const u16* __restrict__ Qhi, const u16* __restrict__ Qlo,
    long base, int i0, int j0,
    u16* Ab0, u16* Bb0, u16* Ab1, u16* Bb1,
    f32x4 (&acc)[4][4], int tid)
{
    const int l = tid & 63, w = tid >> 6;
    const int wm = w & 1, wn = w >> 1;
    const int lrow = l & 15, lk8 = (l >> 4) << 3;

    #pragma unroll
    for (int a = 0; a < 4; ++a)
        #pragma unroll
        for (int bb = 0; bb < 4; ++bb)
            #pragma unroll
            for (int r = 0; r < 4; ++r) acc[a][bb][r] = 0.f;

    // wave 0,1 stage A(K); wave 2,3 stage B(Q). chunk c = (w&1)*8+q, half=q&1
    const u16* hiP = wn ? Qhi : Khi;
    const u16* loP = wn ? Qlo : Klo;
    const int  t0  = wn ? j0 : i0;
    long rowoff[4];
    #pragma unroll
    for (int m2 = 0; m2 < 4; ++m2) {
        const int mt = (w & 1) * 4 + m2;
        rowoff[m2] = base + (long)(t0 + mt * 16 + lrow) * HSn + lk8;
    }
    u16* dst0 = (wn ? Bb0 : Ab0) + (w & 1) * 8 * 512;
    u16* dst1 = (wn ? Bb1 : Ab1) + (w & 1) * 8 * 512;

    auto stage = [&](int h0, u16* dw) {
        #pragma unroll
        for (int q = 0; q < 8; ++q) {
            const u16* sp = (q & 1) ? loP : hiP;
            GLOAD_LDS16(sp + rowoff[q >> 1] + h0, dw + q * 512);
        }
    };
    auto step = [&](const u16* Ab, const u16* Bb) {
        bf16x8 bh[4], bl[4];
        #pragma unroll
        for (int nt = 0; nt < 4; ++nt) {
            const int c2 = (wn * 4 + nt) * 2;
            bh[nt] = *(const bf16x8*)(Bb + (c2    ) * 512 + l * 8);
            bl[nt] = *(const bf16x8*)(Bb + (c2 + 1) * 512 + l * 8);
        }
        #pragma unroll
        for (int mt = 0; mt < 4; ++mt) {
            const int c2 = (wm * 4 + mt) * 2;
            const bf16x8 ah = *(const bf16x8*)(Ab + (c2    ) * 512 + l * 8);
            const bf16x8 al = *(const bf16x8*)(Ab + (c2 + 1) * 512 + l * 8);
            #pragma unroll
            for (int nt = 0; nt < 4; ++nt) {
                acc[mt][nt] = __builtin_amdgcn_mfma_f32_16x16x32_bf16(ah, bh[nt], acc[mt][nt], 0, 0, 0);
                acc[mt][nt] = __builtin_amdgcn_mfma_f32_16x16x32_bf16(ah, bl[nt], acc[mt][nt], 0, 0, 0);
                acc[mt][nt] = __builtin_amdgcn_mfma_f32_16x16x32_bf16(al, bh[nt], acc[mt][nt], 0, 0, 0);
            }
        }
    };

    stage(0, dst0);
    WAITV0_LG0;
    BARRIER;
    #pragma unroll 1
    for (int ks = 0; ks < 8; ks += 2) {
        stage((ks + 1) * 32, dst1);          // prefetch odd step
        step(Ab0, Bb0);
        WAITV0_LG0;                          // prefetch landed + reads retired
        BARRIER;
        if (ks + 2 < 8) stage((ks + 2) * 32, dst0);
        step(Ab1, Bb1);
        WAITV0_LG0;
        BARRIER;
    }
}

__device__ __forceinline__ void pair_from_p(int p, int& it, int& jt) {
    it = (int)((sqrtf(8.f * (float)p + 1.f) - 1.f) * 0.5f);
    while ((it + 1) * (it + 2) / 2 <= p) ++it;
    while (it * (it + 1) / 2 > p) --it;
    jt = p - it * (it + 1) / 2;
}

// ---------------------------------------------------------------------------
// Kernel 2a: per-(pair, column) partial softmax stats (m, d), bf16.
// ---------------------------------------------------------------------------
__global__ __launch_bounds__(256) void stats1_kernel(
    const u16* __restrict__ Khi, const u16* __restrict__ Klo,
    const u16* __restrict__ Qhi, const u16* __restrict__ Qlo,
    u16* __restrict__ Pm, u16* __restrict__ Pd)
{
    __shared__ u16 s_lds[32768];           // 2x(A+B) buffers, 64 KB
    __shared__ float redm[2][128], redd[2][128];

    const int tid = threadIdx.x, l = tid & 63, w = tid >> 6;
    const int wm = w & 1, wn = w >> 1;
    const int b = blockIdx.y;
    int it, jt; pair_from_p(blockIdx.x, it, jt);
    const long base = (long)b * Tn * HSn;

    f32x4 acc[4][4];
    score_tile_mfma(Khi, Klo, Qhi, Qlo, base, it * 128, jt * 128,
                    s_lds, s_lds + 8192, s_lds + 16384, s_lds + 24576, acc, tid);

    const int rquad = (l >> 4) * 4, col = l & 15;
    #pragma unroll
    for (int nt = 0; nt < 4; ++nt) {
        const int j = jt * 128 + wn * 64 + nt * 16 + col;
        float m = NEG_BIG;
        #pragma unroll
        for (int mt = 0; mt < 4; ++mt)
            #pragma unroll
            for (int r = 0; r < 4; ++r) {
                const int i = it * 128 + wm * 64 + mt * 16 + rquad + r;
                const float sv = (i >= j) ? acc[mt][nt][r] * SCALE : NEG_BIG;
                acc[mt][nt][r] = sv;
                m = fmaxf(m, sv);
            }
        m = fmaxf(m, __shfl_xor(m, 16));
        m = fmaxf(m, __shfl_xor(m, 32));
        float d = 0.f;
        #pragma unroll
        for (int mt = 0; mt < 4; ++mt)
            #pragma unroll
            for (int r = 0; r < 4; ++r)
                d += __expf(acc[mt][nt][r] - m);
        d += __shfl_xor(d, 16);
        d += __shfl_xor(d, 32);
        if (l < 16) {
            redm[wm][wn * 64 + nt * 16 + l] = m;
            redd[wm][wn * 64 + nt * 16 + l] = d;
        }
    }
    __syncthreads();
    if (tid < 128) {
        const float m0 = redm[0][tid], m1 = redm[1][tid];
        const float d0 = redd[0][tid], d1 = redd[1][tid];
        const float M = fmaxf(m0, m1);
        float D = d0 * __expf(m0 - M) + d1 * __expf(m1 - M);
        const float Mb = bf16_rn_f(M);
        D *= __expf(M - Mb);      // rebase to the rounded max we will store
        const long idx = ((long)b * NPAIR + blockIdx.x) * 128 + tid;
        Pm[idx] = (u16)(__float_as_uint(Mb) >> 16);
        Pd[idx] = bf16_rn(D);
    }
}

// ---------------------------------------------------------------------------
// Kernel 2b: merge partials over i-tiles -> Ms, Rd.
// ---------------------------------------------------------------------------
__global__ __launch_bounds__(128) void stats2_kernel(
    const u16* __restrict__ Pm, const u16* __restrict__ Pd,
    float* __restrict__ Ms, float* __restrict__ Rd)
{
    const int b = blockIdx.y, jt = blockIdx.x, jl = threadIdx.x;  // 128 threads
    float M = NEG_BIG, D = 0.f;
    for (int it = jt; it < NT; ++it) {
        const int p = it * (it + 1) / 2 + jt;
        const long idx = ((long)b * NPAIR + p) * 128 + jl;
        const float m = __uint_as_float((u32)Pm[idx] << 16);
        const float d = __uint_as_float((u32)Pd[idx] << 16);
        const float Mn = fmaxf(M, m);
        D = D * __expf(M - Mn) + d * __expf(m - Mn);
        M = Mn;
    }
    Ms[(long)b * Tn + jt * 128 + jl] = M;
    Rd[(long)b * Tn + jt * 128 + jl] = 1.f / D;
}

// ---------------------------------------------------------------------------
// Kernel 3: per-pair output partials. V staged frag-native from VbfT via
// gload_lds (transpose moved to projm); Pf unchanged.
// ---------------------------------------------------------------------------
__global__ __launch_bounds__(256) void out_kernel(
    const u16* __restrict__ Khi, const u16* __restrict__ Klo,
    const u16* __restrict__ Qhi, const u16* __restrict__ Qlo,
    const u16* __restrict__ VbfT, const float* __restrict__ Ms,
    const float* __restrict__ Rd, float* __restrict__ Out)
{
    __shared__ u16 u_lds[33792];   // 66 KB: score 2x(A+B)=64 KB | Pf 34 KB + Vfrag 32 KB
    u16* Pf    = u_lds;            // [128][136] bf16
    u16* Vfrag = u_lds + 17408;    // 32 chunks x 512 = 32 KB, layout [kj][hg]

    const int tid = threadIdx.x, l = tid & 63, w = tid >> 6;
    const int wm = w & 1, wn = w >> 1;
    const int lrow = l & 15, lk8 = (l >> 4) << 3;
    const int b = blockIdx.y;
    int it, jt; pair_from_p(blockIdx.x, it, jt);
    const long base = (long)b * Tn * HSn;

    f32x4 acc[4][4];
    score_tile_mfma(Khi, Klo, Qhi, Qlo, base, it * 128, jt * 128,
                    u_lds, u_lds + 8192, u_lds + 16384, u_lds + 24576, acc, tid);

    // wave w stages kj=w, h-group q (16 h x 32 j per chunk)
    auto stage_v = [&](int ph) {
        #pragma unroll
        for (int q = 0; q < 8; ++q) {
            const int hh = ph * 128 + q * 16 + lrow;
            const long ga = ((long)b * HSn + hh) * Tn + jt * 128 + w * 32 + lk8;
            GLOAD_LDS16(VbfT + ga, Vfrag + (w * 8 + q) * 512);
        }
    };

    stage_v(0);   // in flight under Pf computation; drained by next __syncthreads

    const int rquad = (l >> 4) * 4, col = l & 15;
    float mj[4], rj[4];
    #pragma unroll
    for (int nt = 0; nt < 4; ++nt) {
        const int j = jt * 128 + wn * 64 + nt * 16 + col;
        mj[nt] = Ms[(long)b * Tn + j];
        rj[nt] = Rd[(long)b * Tn + j];
    }
    #pragma unroll
    for (int nt = 0; nt < 4; ++nt) {
        const int j = jt * 128 + wn * 64 + nt * 16 + col;
        #pragma unroll
        for (int mt = 0; mt < 4; ++mt)
            #pragma unroll
            for (int r = 0; r < 4; ++r) {
                const int i = it * 128 + wm * 64 + mt * 16 + rquad + r;
                const float pv = (i >= j)
                    ? __expf(acc[mt][nt][r] * SCALE - mj[nt]) * rj[nt] : 0.f;
                Pf[(wm * 64 + mt * 16 + rquad + r) * 136 + wn * 64 + nt * 16 + col]
                    = bf16_rn(pv);
            }
    }

    auto pv_store = [&](int ph) {
        f32x4 o[4][4];
        #pragma unroll
        for (int a = 0; a < 4; ++a)
            #pragma unroll
            for (int bb = 0; bb < 4; ++bb)
                #pragma unroll
                for (int r = 0; r < 4; ++r) o[a][bb][r] = 0.f;
        #pragma unroll
        for (int kj = 0; kj < 4; ++kj) {
            bf16x8 aP[4];
            #pragma unroll
            for (int mt = 0; mt < 4; ++mt)
                aP[mt] = *(const bf16x8*)(Pf + (wm * 64 + mt * 16 + lrow) * 136 + kj * 32 + lk8);
            #pragma unroll
            for (int nt = 0; nt < 4; ++nt) {
                const bf16x8 bV = *(const bf16x8*)(Vfrag + (kj * 8 + wn * 4 + nt) * 512 + l * 8);
                #pragma unroll
                for (int mt = 0; mt < 4; ++mt)
                    o[mt][nt] = __builtin_amdgcn_mfma_f32_16x16x32_bf16(aP[mt], bV, o[mt][nt], 0, 0, 0);
            }
        }
        #pragma unroll
        for (int mt = 0; mt < 4; ++mt)
            #pragma unroll
            for (int nt = 0; nt < 4; ++nt)
                #pragma unroll
                for (int r = 0; r < 4; ++r) {
                    const int i = it * 128 + wm * 64 + mt * 16 + rquad + r;
                    const int h = ph * 128 + wn * 64 + nt * 16 + col;
                    atomicAdd(&Out[((long)b * Tn + i) * HSn + h], o[mt][nt][r]);
                }
    };

    __syncthreads();      // Pf visible + V(ph=0) staged (full drain)
    pv_store(0);
    __syncthreads();      // PV(0) Vfrag reads retired
    stage_v(1);
    __syncthreads();      // V(ph=1) staged
    pv_store(1);
}

extern "C" void kernel_launch(void* const* d_in, const int* in_sizes, int n_in,
                              void* d_out, int out_size, void* d_ws, size_t ws_size,
                              hipStream_t stream) {
    const float* X  = (const float*)d_in[0];
    const float* Wk = (const float*)d_in[1];
    const float* Wq = (const float*)d_in[2];
    const float* Wv = (const float*)d_in[3];

    const long nE = (long)Bn * Tn * HSn;          // 8,388,608 elements
    u16* Khi = (u16*)d_ws;
    u16* Klo = Khi + nE;
    u16* Qhi = Khi + 2 * nE;
    u16* Qlo = Khi + 3 * nE;
    u16* VbfT = Khi + 4 * nE;                     // [b][h][j] transposed bf16 V
    u16* Wt  = Khi + 5 * nE;                      // 6 arrays of WN (hi/lo x K,Q,V)
    u16* Pm  = Wt + 6L * WN;                      // [B][NPAIR][128] bf16
    u16* Pd  = Pm + (long)Bn * NPAIR * 128;
    float* Ms = (float*)(Pd + (long)Bn * NPAIR * 128);
    float* Rd = Ms + (long)Bn * Tn;

    split_w_kernel<<<dim3(Cn, 3), 256, 0, stream>>>(Wk, Wq, Wv, Wt);
    projm_fused_kernel<<<dim3((Bn * Tn) / 128, HSn / 128), 512, 0, stream>>>(
        X, Wt, Khi, Klo, Qhi, Qlo, VbfT);
    stats1_kernel<<<dim3(NPAIR, Bn), 256, 0, stream>>>(Khi, Klo, Qhi, Qlo, Pm, Pd);
    stats2_kernel<<<dim3(NT, Bn), 128, 0, stream>>>(Pm, Pd, Ms, Rd);
    hipMemsetAsync(d_out, 0, (size_t)out_size * sizeof(float), stream);
    out_kernel<<<dim3(NPAIR, Bn), 256, 0, stream>>>(Khi, Klo, Qhi, Qlo, VbfT, Ms, Rd,
                                                    (float*)d_out);
}

// Round 6
// 975.443 us; speedup vs baseline: 1.4621x; 1.0302x over previous
//
#include <hip/hip_runtime.h>
#include <math.h>

#define Bn 16
#define Tn 2048
#define Cn 2048
#define HSn 256
#define SCALE 45.254833995939045f
#define NEG_BIG (-1e30f)
#define NT 16          // number of 128-tiles along T
#define NPAIR 136      // NT*(NT+1)/2
#define WN 524288      // Cn*HSn, elems per W matrix

typedef __attribute__((ext_vector_type(8))) short bf16x8;
typedef __attribute__((ext_vector_type(4))) float f32x4;
typedef unsigned short u16;
typedef unsigned int u32;

__device__ __forceinline__ u16 bf16_rn(float f) {
    u32 u = __float_as_uint(f);
    u += 0x7fffu + ((u >> 16) & 1u);
    return (u16)(u >> 16);
}
__device__ __forceinline__ float bf16_rn_f(float f) {
    return __uint_as_float((u32)bf16_rn(f) << 16);
}

// async global->LDS, 16B per lane; LDS dst is wave-uniform base (+lane*16 implicit)
#define GLOAD_LDS16(gp, lp)                                                      \
    __builtin_amdgcn_global_load_lds(                                            \
        (const __attribute__((address_space(1))) unsigned int*)(gp),             \
        (__attribute__((address_space(3))) unsigned int*)(lp), 16, 0, 0)

#define WAITV0_LG0  asm volatile("s_waitcnt vmcnt(0) lgkmcnt(0)" ::: "memory")
#define WAITV2_LG0  asm volatile("s_waitcnt vmcnt(2) lgkmcnt(0)" ::: "memory")
#define WAITV32_LG0 asm volatile("s_waitcnt vmcnt(32) lgkmcnt(0)" ::: "memory")
#define WAITLG0     asm volatile("s_waitcnt lgkmcnt(0)" ::: "memory")
#define BARRIER     __builtin_amdgcn_s_barrier()

// ---------------------------------------------------------------------------
// Kernel 0: split W matrices into transposed bf16 hi/lo: Wt[mat][n][k].
// Order: KH(0) KL(1) QH(2) QL(3) VH(4) VL(5), each WN elems.
// ---------------------------------------------------------------------------
__global__ __launch_bounds__(256) void split_w_kernel(
    const float* __restrict__ Wk, const float* __restrict__ Wq,
    const float* __restrict__ Wv, u16* __restrict__ Wt)
{
    const int n = threadIdx.x, k = blockIdx.x, mat = blockIdx.y;
    const float* src = (mat == 0) ? Wk : (mat == 1) ? Wq : Wv;
    const float f = src[(long)k * HSn + n];
    const u32 u = __float_as_uint(f);
    const u16 hb = (u16)(u >> 16);                 // truncate -> hi
    const float fh = __uint_as_float(u & 0xffff0000u);
    const u16 lb = bf16_rn(f - fh);                // round residual -> lo
    u16* base = Wt + (long)mat * 2 * WN;
    base[(long)n * Cn + k] = hb;
    base[WN + (long)n * Cn + k] = lb;
}

// ---------------------------------------------------------------------------
// Kernel 1: FUSED K/Q/V projection — 128x128 tile, 8 waves, FULL double-buffer.
// One barrier per 32-k step: stage W(k+1)->B[c^1] (gload_lds) and convert
// X(k+1)->A[c^1] (ds_write) DURING the MFMA phase on buf c; X(k+2) global
// loads stay in flight across 2 steps. LDS 112 KB -> 1 block/CU.
// ---------------------------------------------------------------------------
__global__ __launch_bounds__(512, 2) void projm_fused_kernel(
    const float* __restrict__ X, const u16* __restrict__ Wt,
    u16* __restrict__ Khi, u16* __restrict__ Klo,
    u16* __restrict__ Qhi, u16* __restrict__ Qlo, u16* __restrict__ VbfT)
{
    __shared__ u16 Ahi0[4096], Alo0[4096], Ahi1[4096], Alo1[4096];  // 32 KB
    __shared__ u16 Bb0[20480], Bb1[20480];                          // 80 KB

    const int tid = threadIdx.x, l = tid & 63, w = tid >> 6;   // w in 0..7
    const int wm = w & 3, wn = w >> 2;     // 4 m-quadrants x 2 n-halves
    const int m0 = blockIdx.x * 128, n0 = blockIdx.y * 128;

    // --- X staging offsets: 2 float4 per thread covering 128x32 ---
    int xoff[2], aoff[2];
    #pragma unroll
    for (int p = 0; p < 2; ++p) {
        const int idx4 = p * 512 + tid;     // 0..1023
        const int row  = idx4 >> 3;         // 0..127
        const int kk4  = (idx4 & 7) * 4;    // 0,4,...,28
        xoff[p] = (m0 + row) * Cn + kk4;
        aoff[p] = (row >> 4) * 512 + (((row & 15) | ((kk4 >> 3) << 4)) * 8) + (kk4 & 7);
    }

    // --- W staging: 40 chunks (5 halves x 8 n-chunks); wave w owns g=w*5+j ---
    int wgoff[5];
    const int lbase = w * 5 * 512;
    #pragma unroll
    for (int j = 0; j < 5; ++j) {
        const int g    = w * 5 + j;         // 0..39
        const int half = g >> 3;            // 0:KH 1:KL 2:QH 3:QL 4:VH
        const int cc   = g & 7;             // n-chunk
        const int nrow = n0 + cc * 16 + (l & 15);
        wgoff[j] = half * WN + nrow * Cn + ((l >> 4) << 3);
    }

    f32x4 accK[2][4], accQ[2][4], accV[2][4];
    #pragma unroll
    for (int mt = 0; mt < 2; ++mt)
        #pragma unroll
        for (int nt = 0; nt < 4; ++nt)
            #pragma unroll
            for (int r = 0; r < 4; ++r) {
                accK[mt][nt][r] = 0.f; accQ[mt][nt][r] = 0.f; accV[mt][nt][r] = 0.f;
            }

    float4 xA[2], xB[2];

    auto convert_write = [&](const float4 (&xr)[2], u16* Ah, u16* Al) {
        #pragma unroll
        for (int p = 0; p < 2; ++p) {
            const float xf[4] = {xr[p].x, xr[p].y, xr[p].z, xr[p].w};
            ushort4 h4, l4;
            #pragma unroll
            for (int c = 0; c < 4; ++c) {
                const u32 u = __float_as_uint(xf[c]);
                ((u16*)&h4)[c] = (u16)(u >> 16);
                const float fh = __uint_as_float(u & 0xffff0000u);
                ((u16*)&l4)[c] = bf16_rn(xf[c] - fh);
            }
            *(ushort4*)(Ah + aoff[p]) = h4;
            *(ushort4*)(Al + aoff[p]) = l4;
        }
    };

    auto mfma_all = [&](const u16* Ah, const u16* Al, const u16* Bb) {
        bf16x8 ah[2], al[2];
        #pragma unroll
        for (int mt = 0; mt < 2; ++mt) {
            ah[mt] = *(const bf16x8*)(Ah + (wm * 2 + mt) * 512 + l * 8);
            al[mt] = *(const bf16x8*)(Al + (wm * 2 + mt) * 512 + l * 8);
        }
        {   // K: 3-product
            bf16x8 bh[4], bl[4];
            #pragma unroll
            for (int nt = 0; nt < 4; ++nt) {
                bh[nt] = *(const bf16x8*)(Bb + (0 * 8 + wn * 4 + nt) * 512 + l * 8);
                bl[nt] = *(const bf16x8*)(Bb + (1 * 8 + wn * 4 + nt) * 512 + l * 8);
            }
            #pragma unroll
            for (int mt = 0; mt < 2; ++mt)
                #pragma unroll
                for (int nt = 0; nt < 4; ++nt) {
                    accK[mt][nt] = __builtin_amdgcn_mfma_f32_16x16x32_bf16(ah[mt], bh[nt], accK[mt][nt], 0, 0, 0);
                    accK[mt][nt] = __builtin_amdgcn_mfma_f32_16x16x32_bf16(ah[mt], bl[nt], accK[mt][nt], 0, 0, 0);
                    accK[mt][nt] = __builtin_amdgcn_mfma_f32_16x16x32_bf16(al[mt], bh[nt], accK[mt][nt], 0, 0, 0);
                }
        }
        {   // Q: 3-product
            bf16x8 bh[4], bl[4];
            #pragma unroll
            for (int nt = 0; nt < 4; ++nt) {
                bh[nt] = *(const bf16x8*)(Bb + (2 * 8 + wn * 4 + nt) * 512 + l * 8);
                bl[nt] = *(const bf16x8*)(Bb + (3 * 8 + wn * 4 + nt) * 512 + l * 8);
            }
            #pragma unroll
            for (int mt = 0; mt < 2; ++mt)
                #pragma unroll
                for (int nt = 0; nt < 4; ++nt) {
                    accQ[mt][nt] = __builtin_amdgcn_mfma_f32_16x16x32_bf16(ah[mt], bh[nt], accQ[mt][nt], 0, 0, 0);
                    accQ[mt][nt] = __builtin_amdgcn_mfma_f32_16x16x32_bf16(ah[mt], bl[nt], accQ[mt][nt], 0, 0, 0);
                    accQ[mt][nt] = __builtin_amdgcn_mfma_f32_16x16x32_bf16(al[mt], bh[nt], accQ[mt][nt], 0, 0, 0);
                }
        }
        {   // V: hi only
            bf16x8 bh[4];
            #pragma unroll
            for (int nt = 0; nt < 4; ++nt)
                bh[nt] = *(const bf16x8*)(Bb + (4 * 8 + wn * 4 + nt) * 512 + l * 8);
            #pragma unroll
            for (int mt = 0; mt < 2; ++mt)
                #pragma unroll
                for (int nt = 0; nt < 4; ++nt)
                    accV[mt][nt] = __builtin_amdgcn_mfma_f32_16x16x32_bf16(ah[mt], bh[nt], accV[mt][nt], 0, 0, 0);
        }
    };

    // prologue: stage tile 0 fully; X(32) raw in xB
    xA[0] = *(const float4*)(X + xoff[0]);
    xA[1] = *(const float4*)(X + xoff[1]);
    #pragma unroll
    for (int j = 0; j < 5; ++j)
        GLOAD_LDS16(Wt + wgoff[j], Bb0 + lbase + j * 512);
    xB[0] = *(const float4*)(X + xoff[0] + 32);
    xB[1] = *(const float4*)(X + xoff[1] + 32);
    convert_write(xA, Ahi0, Alo0);          // compiler waits xA only
    WAITV2_LG0;                             // W(0) staged + A(0) written; xB in flight
    BARRIER;

    #pragma unroll 1
    for (int k0 = 0; k0 < Cn; k0 += 64) {
        const int kn  = (k0 + 64 < Cn) ? k0 + 64 : 0;   // clamp: harmless re-stage
        const int kn3 = (k0 + 96 < Cn) ? k0 + 96 : 0;
        // step A: consume buf0 (tile k0); stage buf1 (tile k0+32)
        #pragma unroll
        for (int j = 0; j < 5; ++j)
            GLOAD_LDS16(Wt + wgoff[j] + k0 + 32, Bb1 + lbase + j * 512);
        xA[0] = *(const float4*)(X + xoff[0] + kn);     // X for step after next
        xA[1] = *(const float4*)(X + xoff[1] + kn);
        convert_write(xB, Ahi1, Alo1);                  // A(k0+32); waits xB only
        mfma_all(Ahi0, Alo0, Bb0);
        WAITV2_LG0;                                     // buf1 staged; xA in flight
        BARRIER;
        // step B: consume buf1 (tile k0+32); stage buf0 (tile kn)
        #pragma unroll
        for (int j = 0; j < 5; ++j)
            GLOAD_LDS16(Wt + wgoff[j] + kn, Bb0 + lbase + j * 512);
        xB[0] = *(const float4*)(X + xoff[0] + kn3);
        xB[1] = *(const float4*)(X + xoff[1] + kn3);
        convert_write(xA, Ahi0, Alo0);
        mfma_all(Ahi1, Alo1, Bb1);
        WAITV2_LG0;
        BARRIER;
    }

    // --- epilogue: C/D layout col=l&15, row=(l>>4)*4+r ---
    const int quad = (l >> 4) * 4, col = l & 15;
    u16* Vlds = Bb0;                        // alias: 128x128 bounce (32 KB of 40)
    __syncthreads();                        // full drain (trailing garbage loads)
    #pragma unroll
    for (int mt = 0; mt < 2; ++mt)
        #pragma unroll
        for (int nt = 0; nt < 4; ++nt)
            #pragma unroll
            for (int r = 0; r < 4; ++r) {
                const long i = m0 + wm * 32 + mt * 16 + quad + r;
                const int  j = n0 + wn * 64 + nt * 16 + col;
                {   // K hi/lo
                    const float f = accK[mt][nt][r];
                    const u32 u = __float_as_uint(f);
                    Khi[i * HSn + j] = (u16)(u >> 16);
                    const float fh = __uint_as_float(u & 0xffff0000u);
                    Klo[i * HSn + j] = bf16_rn(f - fh);
                }
                {   // Q hi/lo
                    const float f = accQ[mt][nt][r];
                    const u32 u = __float_as_uint(f);
                    Qhi[i * HSn + j] = (u16)(u >> 16);
                    const float fh = __uint_as_float(u & 0xffff0000u);
                    Qlo[i * HSn + j] = bf16_rn(f - fh);
                }
                Vlds[(wm * 32 + mt * 16 + quad + r) * 128 + wn * 64 + nt * 16 + col]
                    = bf16_rn(accV[mt][nt][r]);
            }
    __syncthreads();
    // transposed V write: VbfT[b][h][j]; hl = LOCAL col (LDS), global h = n0+hl
    {
        const int bidx = m0 >> 11, jb = m0 & (Tn - 1);
        #pragma unroll
        for (int hh = 0; hh < 4; ++hh) {
            const int hl = hh * 32 + (tid >> 4);     // local col 0..127
            const int h  = n0 + hl;                  // global head index
            const int jl = (tid & 15) * 8;           // local j 0..120
            union { uint4 v; u16 s[8]; } pk;
            #pragma unroll
            for (int e = 0; e < 8; ++e) pk.s[e] = Vlds[(jl + e) * 128 + hl];
            *(uint4*)(VbfT + ((long)bidx * HSn + h) * Tn + jb + jl) = pk.v;
        }
    }
}

// ---------------------------------------------------------------------------
// Shared: 128x128 score tile, gload_lds staging, SINGLE buffer (32 KB) —
// occupancy over in-block pipelining: callers now fit 3-4 blocks/CU.
// Numerics identical to validated version.
// ---------------------------------------------------------------------------
__device__ __forceinline__ void score_tile_mfma(
    const u16* __restrict__ Khi, const u16* __restrict__ Klo,
    const u16* __restrict__ Qhi, const u16* __restrict__ Qlo,
    long base, int i0, int j0,
    u16* Ab0, u16* Bb0,
    f32x4 (&acc)[4][4], int tid)
{
    const int l = tid & 63, w = tid >> 6;
    const int wm = w & 1, wn = w >> 1;
    const int lrow = l & 15, lk8 = (l >> 4) << 3;

    #pragma unroll
    for (int a = 0; a < 4; ++a)
        #pragma unroll
        for (int bb = 0; bb < 4; ++bb)
            #pragma unroll
            for (int r = 0; r < 4; ++r) acc[a][bb][r] = 0.f;

    // wave 0,1 stage A(K); wave 2,3 stage B(Q). chunk c = (w&1)*8+q, half=q&1
    const u16* hiP = wn ? Qhi : Khi;
    const u16* loP = wn ? Qlo : Klo;
    const int  t0  = wn ? j0 : i0;
    long rowoff[4];
    #pragma unroll
    for (int m2 = 0; m2 < 4; ++m2) {
        const int mt = (w & 1) * 4 + m2;
        rowoff[m2] = base + (long)(t0 + mt * 16 + lrow) * HSn + lk8;
    }
    u16* dst0 = (wn ? Bb0 : Ab0) + (w & 1) * 8 * 512;

    #pragma unroll 1
    for (int ks = 0; ks < 8; ++ks) {
        const int h0 = ks * 32;
        #pragma unroll
        for (int q = 0; q < 8; ++q) {
            const u16* sp = (q & 1) ? loP : hiP;
            GLOAD_LDS16(sp + rowoff[q >> 1] + h0, dst0 + q * 512);
        }
        WAITV0_LG0;
        BARRIER;
        bf16x8 bh[4], bl[4];
        #pragma unroll
        for (int nt = 0; nt < 4; ++nt) {
            const int c2 = (wn * 4 + nt) * 2;
            bh[nt] = *(const bf16x8*)(Bb0 + (c2    ) * 512 + l * 8);
            bl[nt] = *(const bf16x8*)(Bb0 + (c2 + 1) * 512 + l * 8);
        }
        #pragma unroll
        for (int mt = 0; mt < 4; ++mt) {
            const int c2 = (wm * 4 + mt) * 2;
            const bf16x8 ah = *(const bf16x8*)(Ab0 + (c2    ) * 512 + l * 8);
            const bf16x8 al = *(const bf16x8*)(Ab0 + (c2 + 1) * 512 + l * 8);
            #pragma unroll
            for (int nt = 0; nt < 4; ++nt) {
                acc[mt][nt] = __builtin_amdgcn_mfma_f32_16x16x32_bf16(ah, bh[nt], acc[mt][nt], 0, 0, 0);
                acc[mt][nt] = __builtin_amdgcn_mfma_f32_16x16x32_bf16(ah, bl[nt], acc[mt][nt], 0, 0, 0);
                acc[mt][nt] = __builtin_amdgcn_mfma_f32_16x16x32_bf16(al, bh[nt], acc[mt][nt], 0, 0, 0);
            }
        }
        WAITLG0;          // this wave's frag reads retired before next stage
        BARRIER;
    }
}

__device__ __forceinline__ void pair_from_p(int p, int& it, int& jt) {
    it = (int)((sqrtf(8.f * (float)p + 1.f) - 1.f) * 0.5f);
    while ((it + 1) * (it + 2) / 2 <= p) ++it;
    while (it * (it + 1) / 2 > p) --it;
    jt = p - it * (it + 1) / 2;
}

// ---------------------------------------------------------------------------
// Kernel 2a: per-(pair, column) partial softmax stats (m, d), bf16.
// LDS 34 KB -> 4 blocks/CU.
// ---------------------------------------------------------------------------
__global__ __launch_bounds__(256) void stats1_kernel(
    const u16* __restrict__ Khi, const u16* __restrict__ Klo,
    const u16* __restrict__ Qhi, const u16* __restrict__ Qlo,
    u16* __restrict__ Pm, u16* __restrict__ Pd)
{
    __shared__ u16 s_lds[16384];           // A+B single buffer, 32 KB
    __shared__ float redm[2][128], redd[2][128];

    const int tid = threadIdx.x, l = tid & 63, w = tid >> 6;
    const int wm = w & 1, wn = w >> 1;
    const int b = blockIdx.y;
    int it, jt; pair_from_p(blockIdx.x, it, jt);
    const long base = (long)b * Tn * HSn;

    f32x4 acc[4][4];
    score_tile_mfma(Khi, Klo, Qhi, Qlo, base, it * 128, jt * 128,
                    s_lds, s_lds + 8192, acc, tid);

    const int rquad = (l >> 4) * 4, col = l & 15;
    #pragma unroll
    for (int nt = 0; nt < 4; ++nt) {
        const int j = jt * 128 + wn * 64 + nt * 16 + col;
        float m = NEG_BIG;
        #pragma unroll
        for (int mt = 0; mt < 4; ++mt)
            #pragma unroll
            for (int r = 0; r < 4; ++r) {
                const int i = it * 128 + wm * 64 + mt * 16 + rquad + r;
                const float sv = (i >= j) ? acc[mt][nt][r] * SCALE : NEG_BIG;
                acc[mt][nt][r] = sv;
                m = fmaxf(m, sv);
            }
        m = fmaxf(m, __shfl_xor(m, 16));
        m = fmaxf(m, __shfl_xor(m, 32));
        float d = 0.f;
        #pragma unroll
        for (int mt = 0; mt < 4; ++mt)
            #pragma unroll
            for (int r = 0; r < 4; ++r)
                d += __expf(acc[mt][nt][r] - m);
        d += __shfl_xor(d, 16);
        d += __shfl_xor(d, 32);
        if (l < 16) {
            redm[wm][wn * 64 + nt * 16 + l] = m;
            redd[wm][wn * 64 + nt * 16 + l] = d;
        }
    }
    __syncthreads();
    if (tid < 128) {
        const float m0 = redm[0][tid], m1 = redm[1][tid];
        const float d0 = redd[0][tid], d1 = redd[1][tid];
        const float M = fmaxf(m0, m1);
        float D = d0 * __expf(m0 - M) + d1 * __expf(m1 - M);
        const float Mb = bf16_rn_f(M);
        D *= __expf(M - Mb);      // rebase to the rounded max we will store
        const long idx = ((long)b * NPAIR + blockIdx.x) * 128 + tid;
        Pm[idx] = (u16)(__float_as_uint(Mb) >> 16);
        Pd[idx] = bf16_rn(D);
    }
}

// ---------------------------------------------------------------------------
// Kernel 2b: merge partials over i-tiles -> Ms, Rd.
// ---------------------------------------------------------------------------
__global__ __launch_bounds__(128) void stats2_kernel(
    const u16* __restrict__ Pm, const u16* __restrict__ Pd,
    float* __restrict__ Ms, float* __restrict__ Rd)
{
    const int b = blockIdx.y, jt = blockIdx.x, jl = threadIdx.x;  // 128 threads
    float M = NEG_BIG, D = 0.f;
    for (int it = jt; it < NT; ++it) {
        const int p = it * (it + 1) / 2 + jt;
        const long idx = ((long)b * NPAIR + p) * 128 + jl;
        const float m = __uint_as_float((u32)Pm[idx] << 16);
        const float d = __uint_as_float((u32)Pd[idx] << 16);
        const float Mn = fmaxf(M, m);
        D = D * __expf(M - Mn) + d * __expf(m - Mn);
        M = Mn;
    }
    Ms[(long)b * Tn + jt * 128 + jl] = M;
    Rd[(long)b * Tn + jt * 128 + jl] = 1.f / D;
}

// ---------------------------------------------------------------------------
// Kernel 3: per-pair output partials. 4 PV phases of 64-h (LDS 50 KB ->
// 3 blocks/CU); stage_v(ph+1) issued before phase-ph atomics, counted
// vmcnt(32) waits only the 4 oldest (gloads), atomics never drained in-loop.
// ---------------------------------------------------------------------------
__global__ __launch_bounds__(256) void out_kernel(
    const u16* __restrict__ Khi, const u16* __restrict__ Klo,
    const u16* __restrict__ Qhi, const u16* __restrict__ Qlo,
    const u16* __restrict__ VbfT, const float* __restrict__ Ms,
    const float* __restrict__ Rd, float* __restrict__ Out)
{
    __shared__ u16 u_lds[25600];   // 50 KB: score A+B 32 KB | Pf 34 KB + Vfrag 16 KB
    u16* Pf    = u_lds;            // [128][136] bf16
    u16* Vfrag = u_lds + 17408;    // 16 chunks x 512 = 16 KB (one 64-h phase)

    const int tid = threadIdx.x, l = tid & 63, w = tid >> 6;
    const int wm = w & 1, wn = w >> 1;
    const int lrow = l & 15, lk8 = (l >> 4) << 3;
    const int b = blockIdx.y;
    int it, jt; pair_from_p(blockIdx.x, it, jt);
    const long base = (long)b * Tn * HSn;

    f32x4 acc[4][4];
    score_tile_mfma(Khi, Klo, Qhi, Qlo, base, it * 128, jt * 128,
                    u_lds, u_lds + 8192, acc, tid);

    // wave w stages kj=w; q = 16-h group within the 64-h phase
    auto stage_v = [&](int ph) {
        #pragma unroll
        for (int q = 0; q < 4; ++q) {
            const int hh = ph * 64 + q * 16 + lrow;
            const long ga = ((long)b * HSn + hh) * Tn + jt * 128 + w * 32 + lk8;
            GLOAD_LDS16(VbfT + ga, Vfrag + (w * 4 + q) * 512);
        }
    };

    stage_v(0);   // in flight under Pf computation; drained by __syncthreads

    const int rquad = (l >> 4) * 4, col = l & 15;
    float mj[4], rj[4];
    #pragma unroll
    for (int nt = 0; nt < 4; ++nt) {
        const int j = jt * 128 + wn * 64 + nt * 16 + col;
        mj[nt] = Ms[(long)b * Tn + j];
        rj[nt] = Rd[(long)b * Tn + j];
    }
    #pragma unroll
    for (int nt = 0; nt < 4; ++nt) {
        const int j = jt * 128 + wn * 64 + nt * 16 + col;
        #pragma unroll
        for (int mt = 0; mt < 4; ++mt)
            #pragma unroll
            for (int r = 0; r < 4; ++r) {
                const int i = it * 128 + wm * 64 + mt * 16 + rquad + r;
                const float pv = (i >= j)
                    ? __expf(acc[mt][nt][r] * SCALE - mj[nt]) * rj[nt] : 0.f;
                Pf[(wm * 64 + mt * 16 + rquad + r) * 136 + wn * 64 + nt * 16 + col]
                    = bf16_rn(pv);
            }
    }

    __syncthreads();      // Pf visible + V(ph=0) staged (full drain)

    #pragma unroll 1
    for (int ph = 0; ph < 4; ++ph) {
        f32x4 o[4][2];
        #pragma unroll
        for (int a = 0; a < 4; ++a)
            #pragma unroll
            for (int bb = 0; bb < 2; ++bb)
                #pragma unroll
                for (int r = 0; r < 4; ++r) o[a][bb][r] = 0.f;
        #pragma unroll
        for (int kj = 0; kj < 4; ++kj) {
            bf16x8 aP[4];
            #pragma unroll
            for (int mt = 0; mt < 4; ++mt)
                aP[mt] = *(const bf16x8*)(Pf + (wm * 64 + mt * 16 + lrow) * 136 + kj * 32 + lk8);
            #pragma unroll
            for (int nt = 0; nt < 2; ++nt) {
                const bf16x8 bV = *(const bf16x8*)(Vfrag + (kj * 4 + wn * 2 + nt) * 512 + l * 8);
                #pragma unroll
                for (int mt = 0; mt < 4; ++mt)
                    o[mt][nt] = __builtin_amdgcn_mfma_f32_16x16x32_bf16(aP[mt], bV, o[mt][nt], 0, 0, 0);
            }
        }
        WAITLG0;                       // Vfrag/Pf reads retired
        BARRIER;                       // all waves done reading Vfrag
        if (ph < 3) stage_v(ph + 1);   // DMA next phase (4 gloads, oldest VMEM)
        __builtin_amdgcn_sched_barrier(0);
        #pragma unroll
        for (int mt = 0; mt < 4; ++mt)
            #pragma unroll
            for (int nt = 0; nt < 2; ++nt)
                #pragma unroll
                for (int r = 0; r < 4; ++r) {
                    const int i = it * 128 + wm * 64 + mt * 16 + rquad + r;
                    const int h = ph * 64 + wn * 32 + nt * 16 + col;
                    atomicAdd(&Out[((long)b * Tn + i) * HSn + h], o[mt][nt][r]);
                }
        if (ph < 3) {
            WAITV32_LG0;               // 4 gloads retired; 32 atomics may remain
            BARRIER;                   // Vfrag(ph+1) visible to all
        }
    }
}

extern "C" void kernel_launch(void* const* d_in, const int* in_sizes, int n_in,
                              void* d_out, int out_size, void* d_ws, size_t ws_size,
                              hipStream_t stream) {
    const float* X  = (const float*)d_in[0];
    const float* Wk = (const float*)d_in[1];
    const float* Wq = (const float*)d_in[2];
    const float* Wv = (const float*)d_in[3];

    const long nE = (long)Bn * Tn * HSn;          // 8,388,608 elements
    u16* Khi = (u16*)d_ws;
    u16* Klo = Khi + nE;
    u16* Qhi = Khi + 2 * nE;
    u16* Qlo = Khi + 3 * nE;
    u16* VbfT = Khi + 4 * nE;                     // [b][h][j] transposed bf16 V
    u16* Wt  = Khi + 5 * nE;                      // 6 arrays of WN (hi/lo x K,Q,V)
    u16* Pm  = Wt + 6L * WN;                      // [B][NPAIR][128] bf16
    u16* Pd  = Pm + (long)Bn * NPAIR * 128;
    float* Ms = (float*)(Pd + (long)Bn * NPAIR * 128);
    float* Rd = Ms + (long)Bn * Tn;

    split_w_kernel<<<dim3(Cn, 3), 256, 0, stream>>>(Wk, Wq, Wv, Wt);
    projm_fused_kernel<<<dim3((Bn * Tn) / 128, HSn / 128), 512, 0, stream>>>(
        X, Wt, Khi, Klo, Qhi, Qlo, VbfT);
    stats1_kernel<<<dim3(NPAIR, Bn), 256, 0, stream>>>(Khi, Klo, Qhi, Qlo, Pm, Pd);
    stats2_kernel<<<dim3(NT, Bn), 128, 0, stream>>>(Pm, Pd, Ms, Rd);
    hipMemsetAsync(d_out, 0, (size_t)out_size * sizeof(float), stream);
    out_kernel<<<dim3(NPAIR, Bn), 256, 0, stream>>>(Khi, Klo, Qhi, Qlo, VbfT, Ms, Rd,
                                                    (float*)d_out);
}

// Round 7
// 930.611 us; speedup vs baseline: 1.5326x; 1.0482x over previous
//
#include <hip/hip_runtime.h>
#include <math.h>

#define Bn 16
#define Tn 2048
#define Cn 2048
#define HSn 256
#define SCALE 45.254833995939045f
#define NEG_BIG (-1e30f)
#define NT 16          // number of 128-tiles along T
#define NPAIR 136      // NT*(NT+1)/2
#define WN 524288      // Cn*HSn, elems per W matrix

typedef __attribute__((ext_vector_type(8))) short bf16x8;
typedef __attribute__((ext_vector_type(4))) float f32x4;
typedef unsigned short u16;
typedef unsigned int u32;

__device__ __forceinline__ u16 bf16_rn(float f) {
    u32 u = __float_as_uint(f);
    u += 0x7fffu + ((u >> 16) & 1u);
    return (u16)(u >> 16);
}
__device__ __forceinline__ float bf16_rn_f(float f) {
    return __uint_as_float((u32)bf16_rn(f) << 16);
}

// async global->LDS, 16B per lane; LDS dst is wave-uniform base (+lane*16 implicit)
#define GLOAD_LDS16(gp, lp)                                                      \
    __builtin_amdgcn_global_load_lds(                                            \
        (const __attribute__((address_space(1))) unsigned int*)(gp),             \
        (__attribute__((address_space(3))) unsigned int*)(lp), 16, 0, 0)

#define WAITV0_LG0  asm volatile("s_waitcnt vmcnt(0) lgkmcnt(0)" ::: "memory")
#define WAITV2_LG0  asm volatile("s_waitcnt vmcnt(2) lgkmcnt(0)" ::: "memory")
#define WAITV32_LG0 asm volatile("s_waitcnt vmcnt(32) lgkmcnt(0)" ::: "memory")
#define WAITLG0     asm volatile("s_waitcnt lgkmcnt(0)" ::: "memory")
#define BARRIER     __builtin_amdgcn_s_barrier()

// ===========================================================================
// CHUNK LAYOUTS (pre-swizzled so every gload_lds is one contiguous 1 KB burst)
//   A 512-u16 chunk = one wave fragment group: pos = lane*8 + e, where
//   lane = (row&15) | ((kk>>3)<<4), e = kk&7   (row = 16-row group member,
//   kk = offset within the 32-wide k/h window).
// Kf/Qf: [b][tile(16)][ks(8)][c(16)][512], c = mt8*2 + half (hi/lo)
// Vf   : [b][jt(16)][kj(4)][hg(16)][512]   (kj = 32-row j group, hg = 16-h group)
// Wf   : [half(6)][ntile(2)][kstep(64)][cc(8)][512]
// ===========================================================================

// ---------------------------------------------------------------------------
// Kernel 0: split W into bf16 hi/lo chunks, frag-native global layout.
// ---------------------------------------------------------------------------
__global__ __launch_bounds__(256) void split_w_kernel(
    const float* __restrict__ Wk, const float* __restrict__ Wq,
    const float* __restrict__ Wv, u16* __restrict__ Wf)
{
    const int n = threadIdx.x, k = blockIdx.x, mat = blockIdx.y;
    const float* src = (mat == 0) ? Wk : (mat == 1) ? Wq : Wv;
    const float f = src[(long)k * HSn + n];
    const u32 u = __float_as_uint(f);
    const u16 hb = (u16)(u >> 16);                 // truncate -> hi
    const float fh = __uint_as_float(u & 0xffff0000u);
    const u16 lb = bf16_rn(f - fh);                // round residual -> lo

    const int ntile = n >> 7, cc = (n >> 4) & 7, lrow = n & 15;
    const int kst = k >> 5, kk = k & 31;
    const int pos = ((((kk >> 3) << 4) | lrow) * 8) + (kk & 7);
    const long c0 = (((long)(mat * 2 + 0) * 2 + ntile) * 64 + kst) * 8 + cc;
    const long c1 = c0 + 2 * 64 * 8;               // half+1
    Wf[c0 * 512 + pos] = hb;
    Wf[c1 * 512 + pos] = lb;
}

// ---------------------------------------------------------------------------
// Kernel 1: FUSED K/Q/V projection — 128x128 tile, 8 waves, double-buffered.
// W staging now reads contiguous 1 KB chunks from Wf. Epilogue writes K/Q/V
// directly in chunk layout (V LDS bounce removed).
// ---------------------------------------------------------------------------
__global__ __launch_bounds__(512, 2) void projm_fused_kernel(
    const float* __restrict__ X, const u16* __restrict__ Wf,
    u16* __restrict__ Kf, u16* __restrict__ Qf, u16* __restrict__ Vf)
{
    __shared__ u16 Ahi0[4096], Alo0[4096], Ahi1[4096], Alo1[4096];  // 32 KB
    __shared__ u16 Bb0[20480], Bb1[20480];                          // 80 KB

    const int tid = threadIdx.x, l = tid & 63, w = tid >> 6;   // w in 0..7
    const int wm = w & 3, wn = w >> 2;     // 4 m-quadrants x 2 n-halves
    const int m0 = blockIdx.x * 128, n0 = blockIdx.y * 128;

    // --- X staging offsets: 2 float4 per thread covering 128x32 ---
    int xoff[2], aoff[2];
    #pragma unroll
    for (int p = 0; p < 2; ++p) {
        const int idx4 = p * 512 + tid;     // 0..1023
        const int row  = idx4 >> 3;         // 0..127
        const int kk4  = (idx4 & 7) * 4;    // 0,4,...,28
        xoff[p] = (m0 + row) * Cn + kk4;
        aoff[p] = (row >> 4) * 512 + (((row & 15) | ((kk4 >> 3) << 4)) * 8) + (kk4 & 7);
    }

    // --- W staging: 40 chunks; wave w owns g=w*5+j; contiguous chunk source ---
    int wgoff[5];
    const int lbase = w * 5 * 512;
    #pragma unroll
    for (int j = 0; j < 5; ++j) {
        const int g    = w * 5 + j;         // 0..39
        const int half = g >> 3;            // 0:KH 1:KL 2:QH 3:QL 4:VH
        const int cc   = g & 7;             // n-chunk
        // base chunk offset (without kstep): (half*2+ntile)*64*8*512 + cc*512
        wgoff[j] = (half * 2 + (n0 >> 7)) * 262144 + cc * 512 + l * 8;
    }

    f32x4 accK[2][4], accQ[2][4], accV[2][4];
    #pragma unroll
    for (int mt = 0; mt < 2; ++mt)
        #pragma unroll
        for (int nt = 0; nt < 4; ++nt)
            #pragma unroll
            for (int r = 0; r < 4; ++r) {
                accK[mt][nt][r] = 0.f; accQ[mt][nt][r] = 0.f; accV[mt][nt][r] = 0.f;
            }

    float4 xA[2], xB[2];

    auto convert_write = [&](const float4 (&xr)[2], u16* Ah, u16* Al) {
        #pragma unroll
        for (int p = 0; p < 2; ++p) {
            const float xf[4] = {xr[p].x, xr[p].y, xr[p].z, xr[p].w};
            ushort4 h4, l4;
            #pragma unroll
            for (int c = 0; c < 4; ++c) {
                const u32 u = __float_as_uint(xf[c]);
                ((u16*)&h4)[c] = (u16)(u >> 16);
                const float fh = __uint_as_float(u & 0xffff0000u);
                ((u16*)&l4)[c] = bf16_rn(xf[c] - fh);
            }
            *(ushort4*)(Ah + aoff[p]) = h4;
            *(ushort4*)(Al + aoff[p]) = l4;
        }
    };

    auto mfma_all = [&](const u16* Ah, const u16* Al, const u16* Bb) {
        bf16x8 ah[2], al[2];
        #pragma unroll
        for (int mt = 0; mt < 2; ++mt) {
            ah[mt] = *(const bf16x8*)(Ah + (wm * 2 + mt) * 512 + l * 8);
            al[mt] = *(const bf16x8*)(Al + (wm * 2 + mt) * 512 + l * 8);
        }
        {   // K: 3-product
            bf16x8 bh[4], bl[4];
            #pragma unroll
            for (int nt = 0; nt < 4; ++nt) {
                bh[nt] = *(const bf16x8*)(Bb + (0 * 8 + wn * 4 + nt) * 512 + l * 8);
                bl[nt] = *(const bf16x8*)(Bb + (1 * 8 + wn * 4 + nt) * 512 + l * 8);
            }
            #pragma unroll
            for (int mt = 0; mt < 2; ++mt)
                #pragma unroll
                for (int nt = 0; nt < 4; ++nt) {
                    accK[mt][nt] = __builtin_amdgcn_mfma_f32_16x16x32_bf16(ah[mt], bh[nt], accK[mt][nt], 0, 0, 0);
                    accK[mt][nt] = __builtin_amdgcn_mfma_f32_16x16x32_bf16(ah[mt], bl[nt], accK[mt][nt], 0, 0, 0);
                    accK[mt][nt] = __builtin_amdgcn_mfma_f32_16x16x32_bf16(al[mt], bh[nt], accK[mt][nt], 0, 0, 0);
                }
        }
        {   // Q: 3-product
            bf16x8 bh[4], bl[4];
            #pragma unroll
            for (int nt = 0; nt < 4; ++nt) {
                bh[nt] = *(const bf16x8*)(Bb + (2 * 8 + wn * 4 + nt) * 512 + l * 8);
                bl[nt] = *(const bf16x8*)(Bb + (3 * 8 + wn * 4 + nt) * 512 + l * 8);
            }
            #pragma unroll
            for (int mt = 0; mt < 2; ++mt)
                #pragma unroll
                for (int nt = 0; nt < 4; ++nt) {
                    accQ[mt][nt] = __builtin_amdgcn_mfma_f32_16x16x32_bf16(ah[mt], bh[nt], accQ[mt][nt], 0, 0, 0);
                    accQ[mt][nt] = __builtin_amdgcn_mfma_f32_16x16x32_bf16(ah[mt], bl[nt], accQ[mt][nt], 0, 0, 0);
                    accQ[mt][nt] = __builtin_amdgcn_mfma_f32_16x16x32_bf16(al[mt], bh[nt], accQ[mt][nt], 0, 0, 0);
                }
        }
        {   // V: hi only
            bf16x8 bh[4];
            #pragma unroll
            for (int nt = 0; nt < 4; ++nt)
                bh[nt] = *(const bf16x8*)(Bb + (4 * 8 + wn * 4 + nt) * 512 + l * 8);
            #pragma unroll
            for (int mt = 0; mt < 2; ++mt)
                #pragma unroll
                for (int nt = 0; nt < 4; ++nt)
                    accV[mt][nt] = __builtin_amdgcn_mfma_f32_16x16x32_bf16(ah[mt], bh[nt], accV[mt][nt], 0, 0, 0);
        }
    };

    // prologue: stage tile 0 fully; X(32) raw in xB
    xA[0] = *(const float4*)(X + xoff[0]);
    xA[1] = *(const float4*)(X + xoff[1]);
    #pragma unroll
    for (int j = 0; j < 5; ++j)
        GLOAD_LDS16(Wf + wgoff[j], Bb0 + lbase + j * 512);
    xB[0] = *(const float4*)(X + xoff[0] + 32);
    xB[1] = *(const float4*)(X + xoff[1] + 32);
    convert_write(xA, Ahi0, Alo0);
    WAITV2_LG0;
    BARRIER;

    #pragma unroll 1
    for (int k0 = 0; k0 < Cn; k0 += 64) {
        const int kn  = (k0 + 64 < Cn) ? k0 + 64 : 0;   // clamp: harmless re-stage
        const int kn3 = (k0 + 96 < Cn) ? k0 + 96 : 0;
        // step A: consume buf0 (k0); stage buf1 (k0+32)
        #pragma unroll
        for (int j = 0; j < 5; ++j)
            GLOAD_LDS16(Wf + wgoff[j] + ((k0 + 32) >> 5) * 4096, Bb1 + lbase + j * 512);
        xA[0] = *(const float4*)(X + xoff[0] + kn);
        xA[1] = *(const float4*)(X + xoff[1] + kn);
        convert_write(xB, Ahi1, Alo1);
        mfma_all(Ahi0, Alo0, Bb0);
        WAITV2_LG0;
        BARRIER;
        // step B: consume buf1 (k0+32); stage buf0 (kn)
        #pragma unroll
        for (int j = 0; j < 5; ++j)
            GLOAD_LDS16(Wf + wgoff[j] + (kn >> 5) * 4096, Bb0 + lbase + j * 512);
        xB[0] = *(const float4*)(X + xoff[0] + kn3);
        xB[1] = *(const float4*)(X + xoff[1] + kn3);
        convert_write(xA, Ahi0, Alo0);
        mfma_all(Ahi1, Alo1, Bb1);
        WAITV2_LG0;
        BARRIER;
    }

    // --- epilogue: write K/Q/V in chunk layout directly from registers ---
    const int quad = (l >> 4) * 4, col = l & 15;
    const int bidx = m0 >> 11, tile = (m0 >> 7) & 15;
    const long kqbase = (long)(bidx * 16 + tile) * 128 * 512;
    const long vbase  = (long)(bidx * 16 + tile) * 64 * 512;
    #pragma unroll
    for (int mt = 0; mt < 2; ++mt)
        #pragma unroll
        for (int nt = 0; nt < 4; ++nt)
            #pragma unroll
            for (int r = 0; r < 4; ++r) {
                const int lrow = quad + r;                  // i & 15
                const int mt8  = wm * 2 + mt;               // (i>>4) & 7
                const int ks   = (n0 >> 5) + wn * 2 + (nt >> 1);
                const int hpos = ((((nt & 1) * 2 + (col >> 3)) * 16 + lrow) * 8) + (col & 7);
                const long kqoff = kqbase + (long)(ks * 16 + mt8 * 2) * 512 + hpos;
                {   // K hi/lo
                    const float f = accK[mt][nt][r];
                    const u32 u = __float_as_uint(f);
                    Kf[kqoff]       = (u16)(u >> 16);
                    const float fh = __uint_as_float(u & 0xffff0000u);
                    Kf[kqoff + 512] = bf16_rn(f - fh);
                }
                {   // Q hi/lo
                    const float f = accQ[mt][nt][r];
                    const u32 u = __float_as_uint(f);
                    Qf[kqoff]       = (u16)(u >> 16);
                    const float fh = __uint_as_float(u & 0xffff0000u);
                    Qf[kqoff + 512] = bf16_rn(f - fh);
                }
                {   // V (hi only)
                    const int hg   = (n0 >> 4) + wn * 4 + nt;
                    const int posv = ((col | ((mt * 2 + (lrow >> 3)) << 4)) * 8) + (lrow & 7);
                    Vf[vbase + (long)(wm * 16 + hg) * 512 + posv] = bf16_rn(accV[mt][nt][r]);
                }
            }
}

// ---------------------------------------------------------------------------
// Shared: 128x128 score tile; staging reads contiguous 1 KB chunks from Kf/Qf.
// Single-buffered (occupancy). Numerics identical to validated version.
// ---------------------------------------------------------------------------
__device__ __forceinline__ void score_tile_mfma(
    const u16* __restrict__ Kf, const u16* __restrict__ Qf,
    int b, int it, int jt,
    u16* Ab0, u16* Bb0,
    f32x4 (&acc)[4][4], int tid)
{
    const int l = tid & 63, w = tid >> 6;
    const int wm = w & 1, wn = w >> 1;

    #pragma unroll
    for (int a = 0; a < 4; ++a)
        #pragma unroll
        for (int bb = 0; bb < 4; ++bb)
            #pragma unroll
            for (int r = 0; r < 4; ++r) acc[a][bb][r] = 0.f;

    // wave side: wn=0 stages A(K tile it), wn=1 stages B(Q tile jt).
    // chunk c = (w&1)*8 + q  (== mt8*2 + half, matching producer layout).
    const u16* srcP = wn ? Qf : Kf;
    const long tbase = (long)(b * 16 + (wn ? jt : it)) * 128 * 512
                     + (w & 1) * 8 * 512 + l * 8;
    u16* dst0 = (wn ? Bb0 : Ab0) + (w & 1) * 8 * 512;

    #pragma unroll 1
    for (int ks = 0; ks < 8; ++ks) {
        const long sb = tbase + (long)ks * 16 * 512;
        #pragma unroll
        for (int q = 0; q < 8; ++q)
            GLOAD_LDS16(srcP + sb + q * 512, dst0 + q * 512);
        WAITV0_LG0;
        BARRIER;
        bf16x8 bh[4], bl[4];
        #pragma unroll
        for (int nt = 0; nt < 4; ++nt) {
            const int c2 = (wn * 4 + nt) * 2;
            bh[nt] = *(const bf16x8*)(Bb0 + (c2    ) * 512 + l * 8);
            bl[nt] = *(const bf16x8*)(Bb0 + (c2 + 1) * 512 + l * 8);
        }
        #pragma unroll
        for (int mt = 0; mt < 4; ++mt) {
            const int c2 = (wm * 4 + mt) * 2;
            const bf16x8 ah = *(const bf16x8*)(Ab0 + (c2    ) * 512 + l * 8);
            const bf16x8 al = *(const bf16x8*)(Ab0 + (c2 + 1) * 512 + l * 8);
            #pragma unroll
            for (int nt = 0; nt < 4; ++nt) {
                acc[mt][nt] = __builtin_amdgcn_mfma_f32_16x16x32_bf16(ah, bh[nt], acc[mt][nt], 0, 0, 0);
                acc[mt][nt] = __builtin_amdgcn_mfma_f32_16x16x32_bf16(ah, bl[nt], acc[mt][nt], 0, 0, 0);
                acc[mt][nt] = __builtin_amdgcn_mfma_f32_16x16x32_bf16(al, bh[nt], acc[mt][nt], 0, 0, 0);
            }
        }
        WAITLG0;
        BARRIER;
    }
}

__device__ __forceinline__ void pair_from_p(int p, int& it, int& jt) {
    it = (int)((sqrtf(8.f * (float)p + 1.f) - 1.f) * 0.5f);
    while ((it + 1) * (it + 2) / 2 <= p) ++it;
    while (it * (it + 1) / 2 > p) --it;
    jt = p - it * (it + 1) / 2;
}

// ---------------------------------------------------------------------------
// Kernel 2a: per-(pair, column) partial softmax stats (m, d), bf16.
// ---------------------------------------------------------------------------
__global__ __launch_bounds__(256) void stats1_kernel(
    const u16* __restrict__ Kf, const u16* __restrict__ Qf,
    u16* __restrict__ Pm, u16* __restrict__ Pd)
{
    __shared__ u16 s_lds[16384];           // A+B single buffer, 32 KB
    __shared__ float redm[2][128], redd[2][128];

    const int tid = threadIdx.x, l = tid & 63, w = tid >> 6;
    const int wm = w & 1, wn = w >> 1;
    const int b = blockIdx.y;
    int it, jt; pair_from_p(blockIdx.x, it, jt);

    f32x4 acc[4][4];
    score_tile_mfma(Kf, Qf, b, it, jt, s_lds, s_lds + 8192, acc, tid);

    const int rquad = (l >> 4) * 4, col = l & 15;
    #pragma unroll
    for (int nt = 0; nt < 4; ++nt) {
        const int j = jt * 128 + wn * 64 + nt * 16 + col;
        float m = NEG_BIG;
        #pragma unroll
        for (int mt = 0; mt < 4; ++mt)
            #pragma unroll
            for (int r = 0; r < 4; ++r) {
                const int i = it * 128 + wm * 64 + mt * 16 + rquad + r;
                const float sv = (i >= j) ? acc[mt][nt][r] * SCALE : NEG_BIG;
                acc[mt][nt][r] = sv;
                m = fmaxf(m, sv);
            }
        m = fmaxf(m, __shfl_xor(m, 16));
        m = fmaxf(m, __shfl_xor(m, 32));
        float d = 0.f;
        #pragma unroll
        for (int mt = 0; mt < 4; ++mt)
            #pragma unroll
            for (int r = 0; r < 4; ++r)
                d += __expf(acc[mt][nt][r] - m);
        d += __shfl_xor(d, 16);
        d += __shfl_xor(d, 32);
        if (l < 16) {
            redm[wm][wn * 64 + nt * 16 + l] = m;
            redd[wm][wn * 64 + nt * 16 + l] = d;
        }
    }
    __syncthreads();
    if (tid < 128) {
        const float m0 = redm[0][tid], m1 = redm[1][tid];
        const float d0 = redd[0][tid], d1 = redd[1][tid];
        const float M = fmaxf(m0, m1);
        float D = d0 * __expf(m0 - M) + d1 * __expf(m1 - M);
        const float Mb = bf16_rn_f(M);
        D *= __expf(M - Mb);      // rebase to the rounded max we will store
        const long idx = ((long)b * NPAIR + blockIdx.x) * 128 + tid;
        Pm[idx] = (u16)(__float_as_uint(Mb) >> 16);
        Pd[idx] = bf16_rn(D);
    }
}

// ---------------------------------------------------------------------------
// Kernel 2b: merge partials over i-tiles -> Ms, Rd.
// ---------------------------------------------------------------------------
__global__ __launch_bounds__(128) void stats2_kernel(
    const u16* __restrict__ Pm, const u16* __restrict__ Pd,
    float* __restrict__ Ms, float* __restrict__ Rd)
{
    const int b = blockIdx.y, jt = blockIdx.x, jl = threadIdx.x;  // 128 threads
    float M = NEG_BIG, D = 0.f;
    for (int it = jt; it < NT; ++it) {
        const int p = it * (it + 1) / 2 + jt;
        const long idx = ((long)b * NPAIR + p) * 128 + jl;
        const float m = __uint_as_float((u32)Pm[idx] << 16);
        const float d = __uint_as_float((u32)Pd[idx] << 16);
        const float Mn = fmaxf(M, m);
        D = D * __expf(M - Mn) + d * __expf(m - Mn);
        M = Mn;
    }
    Ms[(long)b * Tn + jt * 128 + jl] = M;
    Rd[(long)b * Tn + jt * 128 + jl] = 1.f / D;
}

// ---------------------------------------------------------------------------
// Kernel 3: per-pair output partials. V staged from chunk-layout Vf
// (contiguous 1 KB per gload). 4 PV phases of 64-h; atomics never drained
// in-loop (counted vmcnt).
// ---------------------------------------------------------------------------
__global__ __launch_bounds__(256) void out_kernel(
    const u16* __restrict__ Kf, const u16* __restrict__ Qf,
    const u16* __restrict__ Vf, const float* __restrict__ Ms,
    const float* __restrict__ Rd, float* __restrict__ Out)
{
    __shared__ u16 u_lds[25600];   // 50 KB: score A+B 32 KB | Pf 34 KB + Vfrag 16 KB
    u16* Pf    = u_lds;            // [128][136] bf16
    u16* Vfrag = u_lds + 17408;    // 16 chunks x 512 = 16 KB (one 64-h phase)

    const int tid = threadIdx.x, l = tid & 63, w = tid >> 6;
    const int wm = w & 1, wn = w >> 1;
    const int lrow = l & 15, lk8 = (l >> 4) << 3;
    const int b = blockIdx.y;
    int it, jt; pair_from_p(blockIdx.x, it, jt);

    f32x4 acc[4][4];
    score_tile_mfma(Kf, Qf, b, it, jt, u_lds, u_lds + 8192, acc, tid);

    // wave w stages kj=w; q = 16-h group within the 64-h phase (contiguous 1 KB)
    const long vb = (long)(b * 16 + jt) * 64 * 512 + (long)w * 16 * 512 + l * 8;
    auto stage_v = [&](int ph) {
        #pragma unroll
        for (int q = 0; q < 4; ++q)
            GLOAD_LDS16(Vf + vb + (ph * 4 + q) * 512, Vfrag + (w * 4 + q) * 512);
    };

    stage_v(0);   // in flight under Pf computation; drained by __syncthreads

    const int rquad = (l >> 4) * 4, col = l & 15;
    float mj[4], rj[4];
    #pragma unroll
    for (int nt = 0; nt < 4; ++nt) {
        const int j = jt * 128 + wn * 64 + nt * 16 + col;
        mj[nt] = Ms[(long)b * Tn + j];
        rj[nt] = Rd[(long)b * Tn + j];
    }
    #pragma unroll
    for (int nt = 0; nt < 4; ++nt) {
        const int j = jt * 128 + wn * 64 + nt * 16 + col;
        #pragma unroll
        for (int mt = 0; mt < 4; ++mt)
            #pragma unroll
            for (int r = 0; r < 4; ++r) {
                const int i = it * 128 + wm * 64 + mt * 16 + rquad + r;
                const float pv = (i >= j)
                    ? __expf(acc[mt][nt][r] * SCALE - mj[nt]) * rj[nt] : 0.f;
                Pf[(wm * 64 + mt * 16 + rquad + r) * 136 + wn * 64 + nt * 16 + col]
                    = bf16_rn(pv);
            }
    }

    __syncthreads();      // Pf visible + V(ph=0) staged (full drain)

    #pragma unroll 1
    for (int ph = 0; ph < 4; ++ph) {
        f32x4 o[4][2];
        #pragma unroll
        for (int a = 0; a < 4; ++a)
            #pragma unroll
            for (int bb = 0; bb < 2; ++bb)
                #pragma unroll
                for (int r = 0; r < 4; ++r) o[a][bb][r] = 0.f;
        #pragma unroll
        for (int kj = 0; kj < 4; ++kj) {
            bf16x8 aP[4];
            #pragma unroll
            for (int mt = 0; mt < 4; ++mt)
                aP[mt] = *(const bf16x8*)(Pf + (wm * 64 + mt * 16 + lrow) * 136 + kj * 32 + lk8);
            #pragma unroll
            for (int nt = 0; nt < 2; ++nt) {
                const bf16x8 bV = *(const bf16x8*)(Vfrag + (kj * 4 + wn * 2 + nt) * 512 + l * 8);
                #pragma unroll
                for (int mt = 0; mt < 4; ++mt)
                    o[mt][nt] = __builtin_amdgcn_mfma_f32_16x16x32_bf16(aP[mt], bV, o[mt][nt], 0, 0, 0);
            }
        }
        WAITLG0;                       // Vfrag/Pf reads retired
        BARRIER;                       // all waves done reading Vfrag
        if (ph < 3) stage_v(ph + 1);   // DMA next phase (4 gloads, oldest VMEM)
        __builtin_amdgcn_sched_barrier(0);
        #pragma unroll
        for (int mt = 0; mt < 4; ++mt)
            #pragma unroll
            for (int nt = 0; nt < 2; ++nt)
                #pragma unroll
                for (int r = 0; r < 4; ++r) {
                    const int i = it * 128 + wm * 64 + mt * 16 + rquad + r;
                    const int h = ph * 64 + wn * 32 + nt * 16 + col;
                    atomicAdd(&Out[((long)b * Tn + i) * HSn + h], o[mt][nt][r]);
                }
        if (ph < 3) {
            WAITV32_LG0;               // 4 gloads retired; 32 atomics may remain
            BARRIER;                   // Vfrag(ph+1) visible to all
        }
    }
}

extern "C" void kernel_launch(void* const* d_in, const int* in_sizes, int n_in,
                              void* d_out, int out_size, void* d_ws, size_t ws_size,
                              hipStream_t stream) {
    const float* X  = (const float*)d_in[0];
    const float* Wk = (const float*)d_in[1];
    const float* Wq = (const float*)d_in[2];
    const float* Wv = (const float*)d_in[3];

    const long nE = (long)Bn * Tn * HSn;          // 8,388,608 elements
    u16* Kf = (u16*)d_ws;                         // 2*nE (hi+lo chunks)
    u16* Qf = Kf + 2 * nE;                        // 2*nE
    u16* Vf = Kf + 4 * nE;                        // nE
    u16* Wf = Kf + 5 * nE;                        // 6*WN
    u16* Pm = Wf + 6L * WN;                       // [B][NPAIR][128] bf16
    u16* Pd = Pm + (long)Bn * NPAIR * 128;
    float* Ms = (float*)(Pd + (long)Bn * NPAIR * 128);
    float* Rd = Ms + (long)Bn * Tn;

    split_w_kernel<<<dim3(Cn, 3), 256, 0, stream>>>(Wk, Wq, Wv, Wf);
    projm_fused_kernel<<<dim3((Bn * Tn) / 128, HSn / 128), 512, 0, stream>>>(
        X, Wf, Kf, Qf, Vf);
    stats1_kernel<<<dim3(NPAIR, Bn), 256, 0, stream>>>(Kf, Qf, Pm, Pd);
    stats2_kernel<<<dim3(NT, Bn), 128, 0, stream>>>(Pm, Pd, Ms, Rd);
    hipMemsetAsync(d_out, 0, (size_t)out_size * sizeof(float), stream);
    out_kernel<<<dim3(NPAIR, Bn), 256, 0, stream>>>(Kf, Qf, Vf, Ms, Rd,
                                                    (float*)d_out);
}